// Round 5
// baseline (262.091 us; speedup 1.0000x reference)
//
#include <hip/hip_runtime.h>
#include <hip/hip_bf16.h>

// Problem constants
#define Bb 32
#define Nn 1024
#define Ff 64
#define Tt 24

// Workspace layout (bytes)
#define LHS_OFF  0
#define RHS_OFF  3145728
#define MKEY_OFF 6291456
#define D0_OFF   6422528
#define ABF_OFF  6426624ull            // sig bf16 [32768][1024] = 64 MiB
#define VB_OFF   73535488ull           // V bf16 [1024][1024] = 2 MiB
#define WS_NEED  75632640ull

typedef __attribute__((ext_vector_type(8))) short bf16x8;
typedef __attribute__((ext_vector_type(4))) float f32x4;
typedef __attribute__((ext_vector_type(16))) float f32x16;

__device__ __forceinline__ unsigned fkey(float x) {
    unsigned u = __float_as_uint(x);
    return (u & 0x80000000u) ? ~u : (u | 0x80000000u);
}
__device__ __forceinline__ float keyToFloat(unsigned k) {
    unsigned u = (k & 0x80000000u) ? (k & 0x7FFFFFFFu) : ~k;
    return __uint_as_float(u);
}
__device__ __forceinline__ unsigned short f2bf(float f) {
    unsigned u = __float_as_uint(f);
    u += 0x7FFFu + ((u >> 16) & 1u);   // round-to-nearest-even
    return (unsigned short)(u >> 16);
}

// K1: fused lhs/rhs computation. One wave per (b,n) row.
__global__ __launch_bounds__(256) void k1_lhs_rhs(
    const float* __restrict__ x, const float* __restrict__ W1,
    const float* __restrict__ W2, const float* __restrict__ W3,
    float* __restrict__ LHS, float* __restrict__ RHS) {
    __shared__ float sx[4][64][25];
    __shared__ float sy[4][64];
    __shared__ float sW1[24];
    __shared__ float sW2[64][24];
    __shared__ float sW3[64];
    int tid = threadIdx.x;
    if (tid < 24) sW1[tid] = W1[tid];
    if (tid < 64) sW3[tid] = W3[tid];
    for (int j = tid; j < 64 * 24; j += 256) sW2[j / 24][j % 24] = W2[j];
    __syncthreads();

    int w = tid >> 6, lane = tid & 63;
    int row = blockIdx.x * 4 + w;   // b*N+n
    const float* xr = x + (size_t)row * (Ff * Tt) + lane * Tt;
    float4 xv[6];
#pragma unroll
    for (int j = 0; j < 6; ++j) xv[j] = reinterpret_cast<const float4*>(xr)[j];
    float y = 0.f;
#pragma unroll
    for (int j = 0; j < 6; ++j) {
        y += xv[j].x * sW1[j * 4 + 0] + xv[j].y * sW1[j * 4 + 1] +
             xv[j].z * sW1[j * 4 + 2] + xv[j].w * sW1[j * 4 + 3];
    }
#pragma unroll
    for (int j = 0; j < 6; ++j) {
        sx[w][lane][j * 4 + 0] = xv[j].x;
        sx[w][lane][j * 4 + 1] = xv[j].y;
        sx[w][lane][j * 4 + 2] = xv[j].z;
        sx[w][lane][j * 4 + 3] = xv[j].w;
    }
    sy[w][lane] = y;
    __syncthreads();
    if (lane < 24) {
        int t = lane;
        float la = 0.f, ra = 0.f;
#pragma unroll 8
        for (int f = 0; f < 64; ++f) {
            ra += sx[w][f][t] * sW3[f];
            la += sy[w][f] * sW2[f][t];
        }
        LHS[(size_t)row * Tt + t] = la;
        RHS[(size_t)row * Tt + t] = ra;
    }
}

// ---- k_vb: V_s fp32 -> bf16 (row-major [i][k] preserved) ----
__global__ __launch_bounds__(256) void k_vb(const float* __restrict__ V,
                                            unsigned* __restrict__ Vb2) {
    size_t idx = (size_t)blockIdx.x * 256 + threadIdx.x;   // 1M/4 float4s
    float4 v = ((const float4*)V)[idx];
    uint2 o;
    o.x = (unsigned)f2bf(v.x) | ((unsigned)f2bf(v.y) << 16);
    o.y = (unsigned)f2bf(v.z) | ((unsigned)f2bf(v.w) << 16);
    ((uint2*)Vb2)[idx] = o;
}

// ---- K2a: sig[b,n,k] = sigmoid(dot24(LHS[b,n,:],RHS[b,k,:]) + b_s[n,k]) -> bf16 ----
__global__ __launch_bounds__(256) void k2a_sig(
    const float* __restrict__ LHS, const float* __restrict__ RHS,
    const float* __restrict__ b_s, unsigned short* __restrict__ Abf) {
    __shared__ float rst[24][68];   // rhs chunk transposed [t][k], padded
    int tid = threadIdx.x;
    int b = blockIdx.z;
    int n0 = blockIdx.x * 64;
    int kh = blockIdx.y * 512;
    int n = tid >> 2, q = tid & 3;

    float L[24];
    const float* lp = LHS + ((size_t)b * Nn + n0 + n) * Tt;
#pragma unroll
    for (int j = 0; j < 24; ++j) L[j] = lp[j];

    for (int kc = 0; kc < 512; kc += 64) {
        __syncthreads();
        const float* rp = RHS + ((size_t)b * Nn + kh + kc) * Tt;
        for (int e = tid; e < 64 * 24; e += 256) rst[e % 24][e / 24] = rp[e];
        __syncthreads();

        float P[16] = {};
#pragma unroll
        for (int j = 0; j < 24; ++j) {
            float Lj = L[j];
            const float4* rv = (const float4*)&rst[j][q * 16];
            float4 r0 = rv[0], r1 = rv[1], r2 = rv[2], r3 = rv[3];
            P[0]  += Lj * r0.x; P[1]  += Lj * r0.y; P[2]  += Lj * r0.z; P[3]  += Lj * r0.w;
            P[4]  += Lj * r1.x; P[5]  += Lj * r1.y; P[6]  += Lj * r1.z; P[7]  += Lj * r1.w;
            P[8]  += Lj * r2.x; P[9]  += Lj * r2.y; P[10] += Lj * r2.z; P[11] += Lj * r2.w;
            P[12] += Lj * r3.x; P[13] += Lj * r3.y; P[14] += Lj * r3.z; P[15] += Lj * r3.w;
        }
        const float* bp = &b_s[(size_t)(n0 + n) * Nn + kh + kc + q * 16];
        unsigned ow[8];
#pragma unroll
        for (int k4 = 0; k4 < 4; ++k4) {
            float4 bs = ((const float4*)bp)[k4];
            unsigned short s0 = f2bf(1.f / (1.f + __expf(-(P[k4 * 4 + 0] + bs.x))));
            unsigned short s1 = f2bf(1.f / (1.f + __expf(-(P[k4 * 4 + 1] + bs.y))));
            unsigned short s2 = f2bf(1.f / (1.f + __expf(-(P[k4 * 4 + 2] + bs.z))));
            unsigned short s3 = f2bf(1.f / (1.f + __expf(-(P[k4 * 4 + 3] + bs.w))));
            ow[k4 * 2 + 0] = (unsigned)s0 | ((unsigned)s1 << 16);
            ow[k4 * 2 + 1] = (unsigned)s2 | ((unsigned)s3 << 16);
        }
        unsigned short* op = Abf + ((size_t)b * Nn + n0 + n) * Nn + kh + kc + q * 16;
        ((uint4*)op)[0] = make_uint4(ow[0], ow[1], ow[2], ow[3]);
        ((uint4*)op)[1] = make_uint4(ow[4], ow[5], ow[6], ow[7]);
    }
}

// ---- K2b v3: 256x256 tile, 32x32x16 MFMA, 2 fine phases/K-tile, reg pipeline,
// ring-4 LDS (128KiB), counted vmcnt(6), both-sides swizzle chunk^=(row&3). ----
// 512 thr = 8 waves (2m x 4i), wave out 128x64 = 4x2 32x32 frags.
__global__ __launch_bounds__(512, 2) void k2b_mfma256(
    const unsigned short* __restrict__ A, const unsigned short* __restrict__ Vb,
    float* __restrict__ S, unsigned* __restrict__ Mkey) {
    __shared__ __align__(16) unsigned short lds[65536];  // 4 slots x (A 8192 + B 8192)

    const int tid = threadIdx.x, w = tid >> 6, lane = tid & 63;
    const int bid = blockIdx.x;
    const int L = ((bid & 7) << 6) + (bid >> 3);   // T1: 512 blocks, 64/XCD contiguous
    const int i0 = (L & 3) * 256;
    const int m0 = (L >> 2) * 256;
    const int wr = w >> 2, wc = w & 3;

    // staging constants: wave w stages tile rows 32w..32w+31 of A and B
    const int srow = lane >> 2;                             // 0..15
    const int csoff = ((lane & 3) ^ ((lane >> 2) & 3)) * 8; // inverse-swizzled src chunk
    const unsigned short* aS0 = A  + (size_t)(m0 + 32 * w + srow) * 1024 + csoff;
    const unsigned short* aS1 = A  + (size_t)(m0 + 32 * w + 16 + srow) * 1024 + csoff;
    const unsigned short* bS0 = Vb + (size_t)(i0 + 32 * w + srow) * 1024 + csoff;
    const unsigned short* bS1 = Vb + (size_t)(i0 + 32 * w + 16 + srow) * 1024 + csoff;
    const int dA0 = w * 1024, dA1 = w * 1024 + 512;          // + slot (shorts)
    const int dB0 = 8192 + w * 1024, dB1 = 8192 + w * 1024 + 512;

    // read constants (swizzled): chunk' = chunk ^ (row&3), row&3 == lane&3
    const int lane31 = lane & 31;
    const int aRow = (wr * 128 + lane31) * 32;           // + mi*1024 (+slot)
    const int bRow = 8192 + (wc * 64 + lane31) * 32;     // + ni*1024 (+slot)
    const int c0 = (((lane >> 5) + 0) ^ (lane & 3)) * 8; // ks=0
    const int c1 = (((lane >> 5) + 2) ^ (lane & 3)) * 8; // ks=1

#define GLD(src, dstShorts) __builtin_amdgcn_global_load_lds(                      \
        (const __attribute__((address_space(1))) void*)(src),                     \
        (__attribute__((address_space(3))) void*)(lds + (dstShorts)), 16, 0, 0)

    // prologue: stage tiles 0,1,2
#pragma unroll
    for (int t = 0; t < 3; ++t) {
        const int sl = t * 16384;
        GLD(aS0 + t * 32, sl + dA0); GLD(aS1 + t * 32, sl + dA1);
        GLD(bS0 + t * 32, sl + dB0); GLD(bS1 + t * 32, sl + dB1);
    }
    asm volatile("s_waitcnt vmcnt(8)" ::: "memory");   // tile 0 landed (8 = tiles 1,2)
    __builtin_amdgcn_s_barrier();

    // preload frags(tile 0, ks=0)
    bf16x8 a0[4], a1[4], b0[2], b1[2];
#pragma unroll
    for (int mi = 0; mi < 4; ++mi) a0[mi] = *(const bf16x8*)(lds + aRow + mi * 1024 + c0);
#pragma unroll
    for (int ni = 0; ni < 2; ++ni) b0[ni] = *(const bf16x8*)(lds + bRow + ni * 1024 + c0);

    f32x16 acc[4][2] = {};
    aS0 += 96; aS1 += 96; bS0 += 96; bS1 += 96;   // point at tile 3

#pragma unroll 4
    for (int t = 0; t < 32; ++t) {
        const int slot  = (t & 3) * 16384;
        const int slotN = ((t + 1) & 3) * 16384;
        const int slotS = ((t + 3) & 3) * 16384;   // stage dest: consumed in iter t-1

        // ---- phase 0: read frags(t,ks1); stage A(t+3); MFMA ks0 ----
#pragma unroll
        for (int mi = 0; mi < 4; ++mi)
            a1[mi] = *(const bf16x8*)(lds + slot + aRow + mi * 1024 + c1);
#pragma unroll
        for (int ni = 0; ni < 2; ++ni)
            b1[ni] = *(const bf16x8*)(lds + slot + bRow + ni * 1024 + c1);
        GLD(aS0, slotS + dA0); GLD(aS1, slotS + dA1);
        __builtin_amdgcn_s_barrier();
        __builtin_amdgcn_s_setprio(1);
#pragma unroll
        for (int mi = 0; mi < 4; ++mi)
#pragma unroll
            for (int ni = 0; ni < 2; ++ni)
                acc[mi][ni] = __builtin_amdgcn_mfma_f32_32x32x16_bf16(
                    a0[mi], b0[ni], acc[mi][ni], 0, 0, 0);
        __builtin_amdgcn_s_setprio(0);
        // tile t+1 fully landed (6 = B(t+2),A(t+2)... newest: A(t+3),B(t+2),A(t+2))
        asm volatile("s_waitcnt vmcnt(6)" ::: "memory");
        __builtin_amdgcn_s_barrier();

        // ---- phase 1: read frags(t+1,ks0); stage B(t+3); MFMA ks1 ----
#pragma unroll
        for (int mi = 0; mi < 4; ++mi)
            a0[mi] = *(const bf16x8*)(lds + slotN + aRow + mi * 1024 + c0);
#pragma unroll
        for (int ni = 0; ni < 2; ++ni)
            b0[ni] = *(const bf16x8*)(lds + slotN + bRow + ni * 1024 + c0);
        GLD(bS0, slotS + dB0); GLD(bS1, slotS + dB1);
        __builtin_amdgcn_s_barrier();
        __builtin_amdgcn_s_setprio(1);
#pragma unroll
        for (int mi = 0; mi < 4; ++mi)
#pragma unroll
            for (int ni = 0; ni < 2; ++ni)
                acc[mi][ni] = __builtin_amdgcn_mfma_f32_32x32x16_bf16(
                    a1[mi], b1[ni], acc[mi][ni], 0, 0, 0);
        __builtin_amdgcn_s_setprio(0);
        __builtin_amdgcn_s_barrier();

        int adv = (t < 29) ? 32 : 0;   // clamp: re-stage tile 31 into dead slots
        aS0 += adv; aS1 += adv; bS0 += adv; bS1 += adv;
    }
#undef GLD

    // epilogue: D col = lane&31, row = (reg&3) + 8*(reg>>2) + 4*(lane>>5)
    const int colD = i0 + wc * 64 + lane31;
    const int rowB = m0 + wr * 128 + 4 * (lane >> 5);
#pragma unroll
    for (int mi = 0; mi < 4; ++mi)
#pragma unroll
        for (int ni = 0; ni < 2; ++ni) {
            f32x16 v = acc[mi][ni];
#pragma unroll
            for (int reg = 0; reg < 16; ++reg) {
                int r = rowB + mi * 32 + (reg & 3) + 8 * (reg >> 2);
                S[(size_t)r * 1024 + colD + ni * 32] = v[reg];
            }
        }

    // fused column max over this block's 256 m-rows (single batch: m0 multiple of 256)
    int bcol = m0 >> 10;
#pragma unroll
    for (int ni = 0; ni < 2; ++ni) {
        float mx = -3.402823466e38f;
#pragma unroll
        for (int mi = 0; mi < 4; ++mi)
#pragma unroll
            for (int reg = 0; reg < 16; ++reg) mx = fmaxf(mx, acc[mi][ni][reg]);
        mx = fmaxf(mx, __shfl_xor(mx, 32));   // merge row-halves (lane>>5)
        if (lane < 32)
            atomicMax(&Mkey[bcol * Nn + i0 + wc * 64 + ni * 32 + lane31], fkey(mx));
    }
}

// ---- fallback fp32 fused GEMM (used only if ws too small) ----
#define KB 32
__global__ __launch_bounds__(256) void k2_gemm(
    const float* __restrict__ LHS, const float* __restrict__ RHS,
    const float* __restrict__ V_s, const float* __restrict__ b_s,
    float* __restrict__ S) {
    __shared__ float Lst[24][132];
    __shared__ float Rst[24][KB];
    __shared__ float As[KB][132];
    __shared__ float Bs[KB][132];
    int tid = threadIdx.x;
    int b = blockIdx.z;
    int n0 = blockIdx.y * 128;
    int i0 = blockIdx.x * 128;
    const float* lbase = LHS + ((size_t)b * Nn + n0) * Tt;
    for (int lin = tid; lin < 128 * Tt; lin += 256) {
        int r = lin / Tt, t = lin % Tt;
        Lst[t][r] = lbase[lin];
    }
    float acc[8][8] = {};
    int tx = tid & 15, ty = tid >> 4;
    int an = (tid & 31) * 4;
    int ak = (tid >> 5) * 4;
    const float* rbase = RHS + (size_t)b * Nn * Tt;
    for (int k0 = 0; k0 < Nn; k0 += KB) {
        __syncthreads();
        for (int lin = tid; lin < KB * Tt; lin += 256) {
            int r = lin / Tt, t = lin % Tt;
            Rst[t][r] = rbase[(size_t)(k0 + r) * Tt + t];
        }
        for (int l4 = tid; l4 < 128 * (KB / 4); l4 += 256) {
            int i = l4 >> 3, k4 = (l4 & 7) << 2;
            float4 v = *(const float4*)&V_s[(size_t)(i0 + i) * Nn + k0 + k4];
            Bs[k4 + 0][i] = v.x; Bs[k4 + 1][i] = v.y;
            Bs[k4 + 2][i] = v.z; Bs[k4 + 3][i] = v.w;
        }
        __syncthreads();
        float pacc[4][4] = {};
#pragma unroll
        for (int t = 0; t < 24; ++t) {
            float4 lv = *(const float4*)&Lst[t][an];
            float4 rv = *(const float4*)&Rst[t][ak];
            float lvv[4] = {lv.x, lv.y, lv.z, lv.w};
            float rvv[4] = {rv.x, rv.y, rv.z, rv.w};
#pragma unroll
            for (int r = 0; r < 4; ++r)
#pragma unroll
                for (int c = 0; c < 4; ++c) pacc[r][c] += lvv[r] * rvv[c];
        }
#pragma unroll
        for (int r = 0; r < 4; ++r) {
            float4 bs4 = *(const float4*)&b_s[(size_t)(n0 + an + r) * Nn + k0 + ak];
            float bsv[4] = {bs4.x, bs4.y, bs4.z, bs4.w};
#pragma unroll
            for (int c = 0; c < 4; ++c) {
                float p = pacc[r][c] + bsv[c];
                As[ak + c][an + r] = 1.f / (1.f + __expf(-p));
            }
        }
        __syncthreads();
#pragma unroll
        for (int kk = 0; kk < KB; ++kk) {
            float4 a0 = *(const float4*)&As[kk][ty * 4];
            float4 a1 = *(const float4*)&As[kk][ty * 4 + 64];
            float4 b0 = *(const float4*)&Bs[kk][tx * 4];
            float4 b1 = *(const float4*)&Bs[kk][tx * 4 + 64];
            float av[8] = {a0.x, a0.y, a0.z, a0.w, a1.x, a1.y, a1.z, a1.w};
            float bv[8] = {b0.x, b0.y, b0.z, b0.w, b1.x, b1.y, b1.z, b1.w};
#pragma unroll
            for (int r = 0; r < 8; ++r)
#pragma unroll
                for (int c = 0; c < 8; ++c) acc[r][c] += av[r] * bv[c];
        }
    }
#pragma unroll
    for (int r = 0; r < 8; ++r) {
        int nn = ty * 4 + (r & 3) + ((r >> 2) << 6);
        float4* op = (float4*)(S + ((size_t)(b * Nn + n0 + nn)) * Nn + i0 + tx * 4);
        op[0]  = make_float4(acc[r][0], acc[r][1], acc[r][2], acc[r][3]);
        op[16] = make_float4(acc[r][4], acc[r][5], acc[r][6], acc[r][7]);
    }
}

// K3: column max over n per (b,i)  (fallback path only)
__global__ __launch_bounds__(256) void k3_colmax(const float* __restrict__ S,
                                                 unsigned* __restrict__ Mkey) {
    int b = blockIdx.z;
    int i0 = blockIdx.x * 64;
    int nbase = blockIdx.y * 256;
    int ii = threadIdx.x & 63, g = threadIdx.x >> 6;
    const float* p = S + ((size_t)(b * Nn + nbase + g * 64)) * Nn + i0 + ii;
    float m = -3.402823466e38f;
#pragma unroll 4
    for (int n = 0; n < 64; ++n) m = fmaxf(m, p[(size_t)n * Nn]);
    __shared__ float red[4][64];
    red[g][ii] = m;
    __syncthreads();
    if (g == 0) {
        m = fmaxf(fmaxf(red[0][ii], red[1][ii]), fmaxf(red[2][ii], red[3][ii]));
        atomicMax(Mkey + b * Nn + i0 + ii, fkey(m));
    }
}

// K4: D0[i] = sum_n exp(S[0,n,i]-M[0,i])
__global__ __launch_bounds__(256) void k4_denom(const float* __restrict__ S,
                                                const unsigned* __restrict__ Mkey,
                                                float* __restrict__ D0) {
    int i0 = blockIdx.x * 64;
    int ii = threadIdx.x & 63, g = threadIdx.x >> 6;
    float M = keyToFloat(Mkey[i0 + ii]);
    const float* p = S + ((size_t)(g * 256)) * Nn + i0 + ii;
    float s = 0.f;
    for (int n = 0; n < 256; ++n) s += __expf(p[(size_t)n * Nn] - M);
    __shared__ float red[4][64];
    red[g][ii] = s;
    __syncthreads();
    if (g == 0) D0[i0 + ii] = (red[0][ii] + red[1][ii]) + (red[2][ii] + red[3][ii]);
}

// K5: out = exp(S - M[b,i]) / D0[i], in place
__global__ __launch_bounds__(256) void k5_final(float* __restrict__ S,
                                                const unsigned* __restrict__ Mkey,
                                                const float* __restrict__ D0) {
    const size_t total4 = (size_t)Bb * Nn * Nn / 4;
    for (size_t idx = (size_t)blockIdx.x * 256 + threadIdx.x; idx < total4;
         idx += (size_t)gridDim.x * 256) {
        size_t e = idx << 2;
        int i = (int)(e & (Nn - 1));
        int b = (int)(e >> 20);
        float4 s4 = ((const float4*)S)[idx];
        uint4 k4 = *(const uint4*)(Mkey + b * Nn + i);
        float4 d4 = *(const float4*)(D0 + i);
        float4 o;
        o.x = __expf(s4.x - keyToFloat(k4.x)) / d4.x;
        o.y = __expf(s4.y - keyToFloat(k4.y)) / d4.y;
        o.z = __expf(s4.z - keyToFloat(k4.z)) / d4.z;
        o.w = __expf(s4.w - keyToFloat(k4.w)) / d4.w;
        ((float4*)S)[idx] = o;
    }
}

extern "C" void kernel_launch(void* const* d_in, const int* in_sizes, int n_in,
                              void* d_out, int out_size, void* d_ws, size_t ws_size,
                              hipStream_t stream) {
    const float* x   = (const float*)d_in[0];
    const float* W1  = (const float*)d_in[1];
    const float* W2  = (const float*)d_in[2];
    const float* W3  = (const float*)d_in[3];
    const float* b_s = (const float*)d_in[4];
    const float* V_s = (const float*)d_in[5];
    float* out = (float*)d_out;

    char* ws = (char*)d_ws;
    float* LHS = (float*)(ws + LHS_OFF);
    float* RHS = (float*)(ws + RHS_OFF);
    unsigned* Mkey = (unsigned*)(ws + MKEY_OFF);
    float* D0 = (float*)(ws + D0_OFF);

    k1_lhs_rhs<<<Bb * Nn / 4, 256, 0, stream>>>(x, W1, W2, W3, LHS, RHS);
    hipMemsetAsync(Mkey, 0, (size_t)Bb * Nn * sizeof(unsigned), stream);

    if (ws_size >= WS_NEED) {
        unsigned short* Abf = (unsigned short*)(ws + ABF_OFF);
        unsigned short* Vb  = (unsigned short*)(ws + VB_OFF);
        k_vb<<<1024, 256, 0, stream>>>(V_s, (unsigned*)Vb);
        k2a_sig<<<dim3(16, 2, 32), 256, 0, stream>>>(LHS, RHS, b_s, Abf);
        k2b_mfma256<<<512, 512, 0, stream>>>(Abf, Vb, out, Mkey);  // fused colmax
    } else {
        k2_gemm<<<dim3(Nn / 128, Nn / 128, Bb), 256, 0, stream>>>(LHS, RHS, V_s, b_s, out);
        k3_colmax<<<dim3(Nn / 64, 4, Bb), 256, 0, stream>>>(out, Mkey);
    }

    k4_denom<<<Nn / 64, 256, 0, stream>>>(out, Mkey, D0);
    k5_final<<<2048, 256, 0, stream>>>(out, Mkey, D0);
}

// Round 6
// 256.291 us; speedup vs baseline: 1.0226x; 1.0226x over previous
//
#include <hip/hip_runtime.h>
#include <hip/hip_bf16.h>

// Problem constants
#define Bb 32
#define Nn 1024
#define Ff 64
#define Tt 24

// Workspace layout (bytes)
#define LHS_OFF  0
#define RHS_OFF  3145728
#define MKEY_OFF 6291456
#define D0_OFF   6422528
#define ABF_OFF  6426624ull            // sig bf16 [32768][1024] = 64 MiB
#define VB_OFF   73535488ull           // V bf16 [1024][1024] = 2 MiB
#define WS_NEED  75632640ull

typedef __attribute__((ext_vector_type(8))) short bf16x8;
typedef __attribute__((ext_vector_type(4))) float f32x4;
typedef __attribute__((ext_vector_type(16))) float f32x16;

__device__ __forceinline__ unsigned fkey(float x) {
    unsigned u = __float_as_uint(x);
    return (u & 0x80000000u) ? ~u : (u | 0x80000000u);
}
__device__ __forceinline__ float keyToFloat(unsigned k) {
    unsigned u = (k & 0x80000000u) ? (k & 0x7FFFFFFFu) : ~k;
    return __uint_as_float(u);
}
__device__ __forceinline__ unsigned short f2bf(float f) {
    unsigned u = __float_as_uint(f);
    u += 0x7FFFu + ((u >> 16) & 1u);   // round-to-nearest-even
    return (unsigned short)(u >> 16);
}

// K1: fused lhs/rhs computation. One wave per (b,n) row.
__global__ __launch_bounds__(256) void k1_lhs_rhs(
    const float* __restrict__ x, const float* __restrict__ W1,
    const float* __restrict__ W2, const float* __restrict__ W3,
    float* __restrict__ LHS, float* __restrict__ RHS) {
    __shared__ float sx[4][64][25];
    __shared__ float sy[4][64];
    __shared__ float sW1[24];
    __shared__ float sW2[64][24];
    __shared__ float sW3[64];
    int tid = threadIdx.x;
    if (tid < 24) sW1[tid] = W1[tid];
    if (tid < 64) sW3[tid] = W3[tid];
    for (int j = tid; j < 64 * 24; j += 256) sW2[j / 24][j % 24] = W2[j];
    __syncthreads();

    int w = tid >> 6, lane = tid & 63;
    int row = blockIdx.x * 4 + w;   // b*N+n
    const float* xr = x + (size_t)row * (Ff * Tt) + lane * Tt;
    float4 xv[6];
#pragma unroll
    for (int j = 0; j < 6; ++j) xv[j] = reinterpret_cast<const float4*>(xr)[j];
    float y = 0.f;
#pragma unroll
    for (int j = 0; j < 6; ++j) {
        y += xv[j].x * sW1[j * 4 + 0] + xv[j].y * sW1[j * 4 + 1] +
             xv[j].z * sW1[j * 4 + 2] + xv[j].w * sW1[j * 4 + 3];
    }
#pragma unroll
    for (int j = 0; j < 6; ++j) {
        sx[w][lane][j * 4 + 0] = xv[j].x;
        sx[w][lane][j * 4 + 1] = xv[j].y;
        sx[w][lane][j * 4 + 2] = xv[j].z;
        sx[w][lane][j * 4 + 3] = xv[j].w;
    }
    sy[w][lane] = y;
    __syncthreads();
    if (lane < 24) {
        int t = lane;
        float la = 0.f, ra = 0.f;
#pragma unroll 8
        for (int f = 0; f < 64; ++f) {
            ra += sx[w][f][t] * sW3[f];
            la += sy[w][f] * sW2[f][t];
        }
        LHS[(size_t)row * Tt + t] = la;
        RHS[(size_t)row * Tt + t] = ra;
    }
}

// ---- k_vb: V_s fp32 -> bf16 (row-major [i][k] preserved) ----
__global__ __launch_bounds__(256) void k_vb(const float* __restrict__ V,
                                            unsigned* __restrict__ Vb2) {
    size_t idx = (size_t)blockIdx.x * 256 + threadIdx.x;   // 1M/4 float4s
    float4 v = ((const float4*)V)[idx];
    uint2 o;
    o.x = (unsigned)f2bf(v.x) | ((unsigned)f2bf(v.y) << 16);
    o.y = (unsigned)f2bf(v.z) | ((unsigned)f2bf(v.w) << 16);
    ((uint2*)Vb2)[idx] = o;
}

// ---- K2a: sig[b,n,k] = sigmoid(dot24(LHS[b,n,:],RHS[b,k,:]) + b_s[n,k]) -> bf16 ----
__global__ __launch_bounds__(256) void k2a_sig(
    const float* __restrict__ LHS, const float* __restrict__ RHS,
    const float* __restrict__ b_s, unsigned short* __restrict__ Abf) {
    __shared__ float rst[24][68];   // rhs chunk transposed [t][k], padded
    int tid = threadIdx.x;
    int b = blockIdx.z;
    int n0 = blockIdx.x * 64;
    int kh = blockIdx.y * 512;
    int n = tid >> 2, q = tid & 3;

    float L[24];
    const float* lp = LHS + ((size_t)b * Nn + n0 + n) * Tt;
#pragma unroll
    for (int j = 0; j < 24; ++j) L[j] = lp[j];

    for (int kc = 0; kc < 512; kc += 64) {
        __syncthreads();
        const float* rp = RHS + ((size_t)b * Nn + kh + kc) * Tt;
        for (int e = tid; e < 64 * 24; e += 256) rst[e % 24][e / 24] = rp[e];
        __syncthreads();

        float P[16] = {};
#pragma unroll
        for (int j = 0; j < 24; ++j) {
            float Lj = L[j];
            const float4* rv = (const float4*)&rst[j][q * 16];
            float4 r0 = rv[0], r1 = rv[1], r2 = rv[2], r3 = rv[3];
            P[0]  += Lj * r0.x; P[1]  += Lj * r0.y; P[2]  += Lj * r0.z; P[3]  += Lj * r0.w;
            P[4]  += Lj * r1.x; P[5]  += Lj * r1.y; P[6]  += Lj * r1.z; P[7]  += Lj * r1.w;
            P[8]  += Lj * r2.x; P[9]  += Lj * r2.y; P[10] += Lj * r2.z; P[11] += Lj * r2.w;
            P[12] += Lj * r3.x; P[13] += Lj * r3.y; P[14] += Lj * r3.z; P[15] += Lj * r3.w;
        }
        const float* bp = &b_s[(size_t)(n0 + n) * Nn + kh + kc + q * 16];
        unsigned ow[8];
#pragma unroll
        for (int k4 = 0; k4 < 4; ++k4) {
            float4 bs = ((const float4*)bp)[k4];
            unsigned short s0 = f2bf(1.f / (1.f + __expf(-(P[k4 * 4 + 0] + bs.x))));
            unsigned short s1 = f2bf(1.f / (1.f + __expf(-(P[k4 * 4 + 1] + bs.y))));
            unsigned short s2 = f2bf(1.f / (1.f + __expf(-(P[k4 * 4 + 2] + bs.z))));
            unsigned short s3 = f2bf(1.f / (1.f + __expf(-(P[k4 * 4 + 3] + bs.w))));
            ow[k4 * 2 + 0] = (unsigned)s0 | ((unsigned)s1 << 16);
            ow[k4 * 2 + 1] = (unsigned)s2 | ((unsigned)s3 << 16);
        }
        unsigned short* op = Abf + ((size_t)b * Nn + n0 + n) * Nn + kh + kc + q * 16;
        ((uint4*)op)[0] = make_uint4(ow[0], ow[1], ow[2], ow[3]);
        ((uint4*)op)[1] = make_uint4(ow[4], ow[5], ow[6], ow[7]);
    }
}

// ---- K2b v4: 256x256 tile, 32x32x16 MFMA, ring-4 LDS, ONE vmcnt(6)+barrier
// per K-tile, reg pipeline one phase ahead, conflict-free swizzle:
//   LDS(row, c) holds global chunk c ^ ((row>>1)&3)   (16B chunks, 4/row)
//   stage: linear dest, source chunk (lane&3)^((lane>>3)&3)
//   read:  chunk' = cg ^ ((lane>>1)&3)  -> 2 lanes/bank-bucket per quarter (free)
__global__ __launch_bounds__(512, 2) void k2b_mfma256(
    const unsigned short* __restrict__ A, const unsigned short* __restrict__ Vb,
    float* __restrict__ S, unsigned* __restrict__ Mkey) {
    __shared__ __align__(16) unsigned short lds[4 * 16384];  // 128 KiB, 4 ring slots

    const int tid = threadIdx.x, w = tid >> 6, lane = tid & 63;
    const int bid = blockIdx.x;
    const int L = ((bid & 7) << 6) + (bid >> 3);   // T1: 64 contiguous tiles per XCD
    const int i0 = (L & 3) * 256;
    const int m0 = (L >> 2) * 256;
    const int wr = w >> 2, wc = w & 3;

    // staging: wave w owns tile rows 32w..32w+31 of A and B
    const int srow = lane >> 2;                               // 0..15
    const int csoff = ((lane & 3) ^ ((lane >> 3) & 3)) * 8;   // inverse-swizzled src
    const unsigned short* aS0 = A  + (size_t)(m0 + 32 * w + srow) * 1024 + csoff;
    const unsigned short* aS1 = A  + (size_t)(m0 + 32 * w + 16 + srow) * 1024 + csoff;
    const unsigned short* bS0 = Vb + (size_t)(i0 + 32 * w + srow) * 1024 + csoff;
    const unsigned short* bS1 = Vb + (size_t)(i0 + 32 * w + 16 + srow) * 1024 + csoff;
    const int dA0 = w * 1024, dA1 = w * 1024 + 512;           // shorts, + slot base
    const int dB0 = 8192 + w * 1024, dB1 = 8192 + w * 1024 + 512;

    // read constants
    const int lane31 = lane & 31;
    const int swz = (lane >> 1) & 3;
    const int aRow = (wr * 128 + lane31) * 32;            // + mi*1024 + slot
    const int bRow = 8192 + (wc * 64 + lane31) * 32;      // + ni*1024 + slot
    const int c0 = (((lane >> 5) + 0) ^ swz) * 8;         // ks=0 chunks {0,1}
    const int c1 = (((lane >> 5) + 2) ^ swz) * 8;         // ks=1 chunks {2,3}

#define GLD(src, dstShorts) __builtin_amdgcn_global_load_lds(                      \
        (const __attribute__((address_space(1))) void*)(src),                     \
        (__attribute__((address_space(3))) void*)(lds + (dstShorts)), 16, 0, 0)

    // prologue: stage tiles 0,1,2
#pragma unroll
    for (int t = 0; t < 3; ++t) {
        const int sl = t * 16384;
        GLD(aS0 + t * 32, sl + dA0); GLD(aS1 + t * 32, sl + dA1);
        GLD(bS0 + t * 32, sl + dB0); GLD(bS1 + t * 32, sl + dB1);
    }
    asm volatile("s_waitcnt vmcnt(8)" ::: "memory");   // tile 0 landed
    __builtin_amdgcn_s_barrier();

    // preload frags(tile 0, ks=0)
    bf16x8 a0[4], a1[4], b0[2], b1[2];
#pragma unroll
    for (int mi = 0; mi < 4; ++mi) a0[mi] = *(const bf16x8*)(lds + aRow + mi * 1024 + c0);
#pragma unroll
    for (int ni = 0; ni < 2; ++ni) b0[ni] = *(const bf16x8*)(lds + bRow + ni * 1024 + c0);

    f32x16 acc[4][2] = {};

#pragma unroll 4
    for (int t = 0; t < 32; ++t) {
        const int slot  = (t & 3) * 16384;
        const int slotN = ((t + 1) & 3) * 16384;
        const int slotS = ((t + 3) & 3) * 16384;      // last read before barrier(t-1)
        const int st = (t + 3 < 32) ? (t + 3) * 32 : 31 * 32;   // clamped tail restage

        // ---- phase 0: read frags(t,ks1); stage A(t+3); MFMA ks0 ----
#pragma unroll
        for (int mi = 0; mi < 4; ++mi)
            a1[mi] = *(const bf16x8*)(lds + slot + aRow + mi * 1024 + c1);
#pragma unroll
        for (int ni = 0; ni < 2; ++ni)
            b1[ni] = *(const bf16x8*)(lds + slot + bRow + ni * 1024 + c1);
        GLD(aS0 + st, slotS + dA0); GLD(aS1 + st, slotS + dA1);
        __builtin_amdgcn_s_setprio(1);
#pragma unroll
        for (int mi = 0; mi < 4; ++mi)
#pragma unroll
            for (int ni = 0; ni < 2; ++ni)
                acc[mi][ni] = __builtin_amdgcn_mfma_f32_32x32x16_bf16(
                    a0[mi], b0[ni], acc[mi][ni], 0, 0, 0);
        __builtin_amdgcn_s_setprio(0);
        // publish tile t+1: own 6 newest loads may float (A(t+3),B(t+2),A(t+2))
        asm volatile("s_waitcnt vmcnt(6)" ::: "memory");
        __builtin_amdgcn_s_barrier();

        // ---- phase 1: read frags(t+1,ks0); stage B(t+3); MFMA ks1 ----
#pragma unroll
        for (int mi = 0; mi < 4; ++mi)
            a0[mi] = *(const bf16x8*)(lds + slotN + aRow + mi * 1024 + c0);
#pragma unroll
        for (int ni = 0; ni < 2; ++ni)
            b0[ni] = *(const bf16x8*)(lds + slotN + bRow + ni * 1024 + c0);
        GLD(bS0 + st, slotS + dB0); GLD(bS1 + st, slotS + dB1);
        __builtin_amdgcn_s_setprio(1);
#pragma unroll
        for (int mi = 0; mi < 4; ++mi)
#pragma unroll
            for (int ni = 0; ni < 2; ++ni)
                acc[mi][ni] = __builtin_amdgcn_mfma_f32_32x32x16_bf16(
                    a1[mi], b1[ni], acc[mi][ni], 0, 0, 0);
        __builtin_amdgcn_s_setprio(0);
    }
#undef GLD

    // epilogue: D col = lane&31, row = (reg&3) + 8*(reg>>2) + 4*(lane>>5)
    const int colD = i0 + wc * 64 + lane31;
    const int rowB = m0 + wr * 128 + 4 * (lane >> 5);
#pragma unroll
    for (int mi = 0; mi < 4; ++mi)
#pragma unroll
        for (int ni = 0; ni < 2; ++ni) {
            f32x16 v = acc[mi][ni];
#pragma unroll
            for (int reg = 0; reg < 16; ++reg) {
                int r = rowB + mi * 32 + (reg & 3) + 8 * (reg >> 2);
                S[(size_t)r * 1024 + colD + ni * 32] = v[reg];
            }
        }

    // fused column max over this block's 256 m-rows (single batch per tile)
    int bcol = m0 >> 10;
#pragma unroll
    for (int ni = 0; ni < 2; ++ni) {
        float mx = -3.402823466e38f;
#pragma unroll
        for (int mi = 0; mi < 4; ++mi)
#pragma unroll
            for (int reg = 0; reg < 16; ++reg) mx = fmaxf(mx, acc[mi][ni][reg]);
        mx = fmaxf(mx, __shfl_xor(mx, 32));   // merge row-halves
        if (lane < 32)
            atomicMax(&Mkey[bcol * Nn + i0 + wc * 64 + ni * 32 + lane31], fkey(mx));
    }
}

// ---- fallback fp32 fused GEMM (used only if ws too small) ----
#define KB 32
__global__ __launch_bounds__(256) void k2_gemm(
    const float* __restrict__ LHS, const float* __restrict__ RHS,
    const float* __restrict__ V_s, const float* __restrict__ b_s,
    float* __restrict__ S) {
    __shared__ float Lst[24][132];
    __shared__ float Rst[24][KB];
    __shared__ float As[KB][132];
    __shared__ float Bs[KB][132];
    int tid = threadIdx.x;
    int b = blockIdx.z;
    int n0 = blockIdx.y * 128;
    int i0 = blockIdx.x * 128;
    const float* lbase = LHS + ((size_t)b * Nn + n0) * Tt;
    for (int lin = tid; lin < 128 * Tt; lin += 256) {
        int r = lin / Tt, t = lin % Tt;
        Lst[t][r] = lbase[lin];
    }
    float acc[8][8] = {};
    int tx = tid & 15, ty = tid >> 4;
    int an = (tid & 31) * 4;
    int ak = (tid >> 5) * 4;
    const float* rbase = RHS + (size_t)b * Nn * Tt;
    for (int k0 = 0; k0 < Nn; k0 += KB) {
        __syncthreads();
        for (int lin = tid; lin < KB * Tt; lin += 256) {
            int r = lin / Tt, t = lin % Tt;
            Rst[t][r] = rbase[(size_t)(k0 + r) * Tt + t];
        }
        for (int l4 = tid; l4 < 128 * (KB / 4); l4 += 256) {
            int i = l4 >> 3, k4 = (l4 & 7) << 2;
            float4 v = *(const float4*)&V_s[(size_t)(i0 + i) * Nn + k0 + k4];
            Bs[k4 + 0][i] = v.x; Bs[k4 + 1][i] = v.y;
            Bs[k4 + 2][i] = v.z; Bs[k4 + 3][i] = v.w;
        }
        __syncthreads();
        float pacc[4][4] = {};
#pragma unroll
        for (int t = 0; t < 24; ++t) {
            float4 lv = *(const float4*)&Lst[t][an];
            float4 rv = *(const float4*)&Rst[t][ak];
            float lvv[4] = {lv.x, lv.y, lv.z, lv.w};
            float rvv[4] = {rv.x, rv.y, rv.z, rv.w};
#pragma unroll
            for (int r = 0; r < 4; ++r)
#pragma unroll
                for (int c = 0; c < 4; ++c) pacc[r][c] += lvv[r] * rvv[c];
        }
#pragma unroll
        for (int r = 0; r < 4; ++r) {
            float4 bs4 = *(const float4*)&b_s[(size_t)(n0 + an + r) * Nn + k0 + ak];
            float bsv[4] = {bs4.x, bs4.y, bs4.z, bs4.w};
#pragma unroll
            for (int c = 0; c < 4; ++c) {
                float p = pacc[r][c] + bsv[c];
                As[ak + c][an + r] = 1.f / (1.f + __expf(-p));
            }
        }
        __syncthreads();
#pragma unroll
        for (int kk = 0; kk < KB; ++kk) {
            float4 a0 = *(const float4*)&As[kk][ty * 4];
            float4 a1 = *(const float4*)&As[kk][ty * 4 + 64];
            float4 b0 = *(const float4*)&Bs[kk][tx * 4];
            float4 b1 = *(const float4*)&Bs[kk][tx * 4 + 64];
            float av[8] = {a0.x, a0.y, a0.z, a0.w, a1.x, a1.y, a1.z, a1.w};
            float bv[8] = {b0.x, b0.y, b0.z, b0.w, b1.x, b1.y, b1.z, b1.w};
#pragma unroll
            for (int r = 0; r < 8; ++r)
#pragma unroll
                for (int c = 0; c < 8; ++c) acc[r][c] += av[r] * bv[c];
        }
    }
#pragma unroll
    for (int r = 0; r < 8; ++r) {
        int nn = ty * 4 + (r & 3) + ((r >> 2) << 6);
        float4* op = (float4*)(S + ((size_t)(b * Nn + n0 + nn)) * Nn + i0 + tx * 4);
        op[0]  = make_float4(acc[r][0], acc[r][1], acc[r][2], acc[r][3]);
        op[16] = make_float4(acc[r][4], acc[r][5], acc[r][6], acc[r][7]);
    }
}

// K3: column max over n per (b,i)  (fallback path only)
__global__ __launch_bounds__(256) void k3_colmax(const float* __restrict__ S,
                                                 unsigned* __restrict__ Mkey) {
    int b = blockIdx.z;
    int i0 = blockIdx.x * 64;
    int nbase = blockIdx.y * 256;
    int ii = threadIdx.x & 63, g = threadIdx.x >> 6;
    const float* p = S + ((size_t)(b * Nn + nbase + g * 64)) * Nn + i0 + ii;
    float m = -3.402823466e38f;
#pragma unroll 4
    for (int n = 0; n < 64; ++n) m = fmaxf(m, p[(size_t)n * Nn]);
    __shared__ float red[4][64];
    red[g][ii] = m;
    __syncthreads();
    if (g == 0) {
        m = fmaxf(fmaxf(red[0][ii], red[1][ii]), fmaxf(red[2][ii], red[3][ii]));
        atomicMax(Mkey + b * Nn + i0 + ii, fkey(m));
    }
}

// K4: D0[i] = sum_n exp(S[0,n,i]-M[0,i])
__global__ __launch_bounds__(256) void k4_denom(const float* __restrict__ S,
                                                const unsigned* __restrict__ Mkey,
                                                float* __restrict__ D0) {
    int i0 = blockIdx.x * 64;
    int ii = threadIdx.x & 63, g = threadIdx.x >> 6;
    float M = keyToFloat(Mkey[i0 + ii]);
    const float* p = S + ((size_t)(g * 256)) * Nn + i0 + ii;
    float s = 0.f;
    for (int n = 0; n < 256; ++n) s += __expf(p[(size_t)n * Nn] - M);
    __shared__ float red[4][64];
    red[g][ii] = s;
    __syncthreads();
    if (g == 0) D0[i0 + ii] = (red[0][ii] + red[1][ii]) + (red[2][ii] + red[3][ii]);
}

// K5: out = exp(S - M[b,i]) / D0[i], in place
__global__ __launch_bounds__(256) void k5_final(float* __restrict__ S,
                                                const unsigned* __restrict__ Mkey,
                                                const float* __restrict__ D0) {
    const size_t total4 = (size_t)Bb * Nn * Nn / 4;
    for (size_t idx = (size_t)blockIdx.x * 256 + threadIdx.x; idx < total4;
         idx += (size_t)gridDim.x * 256) {
        size_t e = idx << 2;
        int i = (int)(e & (Nn - 1));
        int b = (int)(e >> 20);
        float4 s4 = ((const float4*)S)[idx];
        uint4 k4 = *(const uint4*)(Mkey + b * Nn + i);
        float4 d4 = *(const float4*)(D0 + i);
        float4 o;
        o.x = __expf(s4.x - keyToFloat(k4.x)) / d4.x;
        o.y = __expf(s4.y - keyToFloat(k4.y)) / d4.y;
        o.z = __expf(s4.z - keyToFloat(k4.z)) / d4.z;
        o.w = __expf(s4.w - keyToFloat(k4.w)) / d4.w;
        ((float4*)S)[idx] = o;
    }
}

extern "C" void kernel_launch(void* const* d_in, const int* in_sizes, int n_in,
                              void* d_out, int out_size, void* d_ws, size_t ws_size,
                              hipStream_t stream) {
    const float* x   = (const float*)d_in[0];
    const float* W1  = (const float*)d_in[1];
    const float* W2  = (const float*)d_in[2];
    const float* W3  = (const float*)d_in[3];
    const float* b_s = (const float*)d_in[4];
    const float* V_s = (const float*)d_in[5];
    float* out = (float*)d_out;

    char* ws = (char*)d_ws;
    float* LHS = (float*)(ws + LHS_OFF);
    float* RHS = (float*)(ws + RHS_OFF);
    unsigned* Mkey = (unsigned*)(ws + MKEY_OFF);
    float* D0 = (float*)(ws + D0_OFF);

    k1_lhs_rhs<<<Bb * Nn / 4, 256, 0, stream>>>(x, W1, W2, W3, LHS, RHS);
    hipMemsetAsync(Mkey, 0, (size_t)Bb * Nn * sizeof(unsigned), stream);

    if (ws_size >= WS_NEED) {
        unsigned short* Abf = (unsigned short*)(ws + ABF_OFF);
        unsigned short* Vb  = (unsigned short*)(ws + VB_OFF);
        k_vb<<<1024, 256, 0, stream>>>(V_s, (unsigned*)Vb);
        k2a_sig<<<dim3(16, 2, 32), 256, 0, stream>>>(LHS, RHS, b_s, Abf);
        k2b_mfma256<<<512, 512, 0, stream>>>(Abf, Vb, out, Mkey);  // fused colmax
    } else {
        k2_gemm<<<dim3(Nn / 128, Nn / 128, Bb), 256, 0, stream>>>(LHS, RHS, V_s, b_s, out);
        k3_colmax<<<dim3(Nn / 64, 4, Bb), 256, 0, stream>>>(out, Mkey);
    }

    k4_denom<<<Nn / 64, 256, 0, stream>>>(out, Mkey, D0);
    k5_final<<<2048, 256, 0, stream>>>(out, Mkey, D0);
}

// Round 7
// 249.610 us; speedup vs baseline: 1.0500x; 1.0268x over previous
//
#include <hip/hip_runtime.h>
#include <hip/hip_bf16.h>

// Problem constants
#define Bb 32
#define Nn 1024
#define Ff 64
#define Tt 24

// Workspace layout (bytes)
#define LHS_OFF  0
#define RHS_OFF  3145728
#define MKEY_OFF 6291456
#define D0_OFF   6422528
#define ABF_OFF  6426624ull            // sig bf16 [32768][1024] = 64 MiB
#define VB_OFF   73535488ull           // V bf16 [1024][1024] = 2 MiB
#define WS_NEED  75632640ull

typedef __attribute__((ext_vector_type(8))) short bf16x8;
typedef __attribute__((ext_vector_type(4))) float f32x4;

__device__ __forceinline__ unsigned fkey(float x) {
    unsigned u = __float_as_uint(x);
    return (u & 0x80000000u) ? ~u : (u | 0x80000000u);
}
__device__ __forceinline__ float keyToFloat(unsigned k) {
    unsigned u = (k & 0x80000000u) ? (k & 0x7FFFFFFFu) : ~k;
    return __uint_as_float(u);
}
__device__ __forceinline__ unsigned short f2bf(float f) {
    unsigned u = __float_as_uint(f);
    u += 0x7FFFu + ((u >> 16) & 1u);   // round-to-nearest-even
    return (unsigned short)(u >> 16);
}

// K1: fused lhs/rhs computation. One wave per (b,n) row.
__global__ __launch_bounds__(256) void k1_lhs_rhs(
    const float* __restrict__ x, const float* __restrict__ W1,
    const float* __restrict__ W2, const float* __restrict__ W3,
    float* __restrict__ LHS, float* __restrict__ RHS) {
    __shared__ float sx[4][64][25];
    __shared__ float sy[4][64];
    __shared__ float sW1[24];
    __shared__ float sW2[64][24];
    __shared__ float sW3[64];
    int tid = threadIdx.x;
    if (tid < 24) sW1[tid] = W1[tid];
    if (tid < 64) sW3[tid] = W3[tid];
    for (int j = tid; j < 64 * 24; j += 256) sW2[j / 24][j % 24] = W2[j];
    __syncthreads();

    int w = tid >> 6, lane = tid & 63;
    int row = blockIdx.x * 4 + w;   // b*N+n
    const float* xr = x + (size_t)row * (Ff * Tt) + lane * Tt;
    float4 xv[6];
#pragma unroll
    for (int j = 0; j < 6; ++j) xv[j] = reinterpret_cast<const float4*>(xr)[j];
    float y = 0.f;
#pragma unroll
    for (int j = 0; j < 6; ++j) {
        y += xv[j].x * sW1[j * 4 + 0] + xv[j].y * sW1[j * 4 + 1] +
             xv[j].z * sW1[j * 4 + 2] + xv[j].w * sW1[j * 4 + 3];
    }
#pragma unroll
    for (int j = 0; j < 6; ++j) {
        sx[w][lane][j * 4 + 0] = xv[j].x;
        sx[w][lane][j * 4 + 1] = xv[j].y;
        sx[w][lane][j * 4 + 2] = xv[j].z;
        sx[w][lane][j * 4 + 3] = xv[j].w;
    }
    sy[w][lane] = y;
    __syncthreads();
    if (lane < 24) {
        int t = lane;
        float la = 0.f, ra = 0.f;
#pragma unroll 8
        for (int f = 0; f < 64; ++f) {
            ra += sx[w][f][t] * sW3[f];
            la += sy[w][f] * sW2[f][t];
        }
        LHS[(size_t)row * Tt + t] = la;
        RHS[(size_t)row * Tt + t] = ra;
    }
}

// ---- k_vb: V_s fp32 -> bf16 (row-major [i][k] preserved) ----
__global__ __launch_bounds__(256) void k_vb(const float* __restrict__ V,
                                            unsigned* __restrict__ Vb2) {
    size_t idx = (size_t)blockIdx.x * 256 + threadIdx.x;   // 1M/4 float4s
    float4 v = ((const float4*)V)[idx];
    uint2 o;
    o.x = (unsigned)f2bf(v.x) | ((unsigned)f2bf(v.y) << 16);
    o.y = (unsigned)f2bf(v.z) | ((unsigned)f2bf(v.w) << 16);
    ((uint2*)Vb2)[idx] = o;
}

// ---- K2a: sig[b,n,k] = sigmoid(dot24(LHS[b,n,:],RHS[b,k,:]) + b_s[n,k]) -> bf16 ----
__global__ __launch_bounds__(256) void k2a_sig(
    const float* __restrict__ LHS, const float* __restrict__ RHS,
    const float* __restrict__ b_s, unsigned short* __restrict__ Abf) {
    __shared__ float rst[24][68];   // rhs chunk transposed [t][k], padded
    int tid = threadIdx.x;
    int b = blockIdx.z;
    int n0 = blockIdx.x * 64;
    int kh = blockIdx.y * 512;
    int n = tid >> 2, q = tid & 3;

    float L[24];
    const float* lp = LHS + ((size_t)b * Nn + n0 + n) * Tt;
#pragma unroll
    for (int j = 0; j < 24; ++j) L[j] = lp[j];

    for (int kc = 0; kc < 512; kc += 64) {
        __syncthreads();
        const float* rp = RHS + ((size_t)b * Nn + kh + kc) * Tt;
        for (int e = tid; e < 64 * 24; e += 256) rst[e % 24][e / 24] = rp[e];
        __syncthreads();

        float P[16] = {};
#pragma unroll
        for (int j = 0; j < 24; ++j) {
            float Lj = L[j];
            const float4* rv = (const float4*)&rst[j][q * 16];
            float4 r0 = rv[0], r1 = rv[1], r2 = rv[2], r3 = rv[3];
            P[0]  += Lj * r0.x; P[1]  += Lj * r0.y; P[2]  += Lj * r0.z; P[3]  += Lj * r0.w;
            P[4]  += Lj * r1.x; P[5]  += Lj * r1.y; P[6]  += Lj * r1.z; P[7]  += Lj * r1.w;
            P[8]  += Lj * r2.x; P[9]  += Lj * r2.y; P[10] += Lj * r2.z; P[11] += Lj * r2.w;
            P[12] += Lj * r3.x; P[13] += Lj * r3.y; P[14] += Lj * r3.z; P[15] += Lj * r3.w;
        }
        const float* bp = &b_s[(size_t)(n0 + n) * Nn + kh + kc + q * 16];
        unsigned ow[8];
#pragma unroll
        for (int k4 = 0; k4 < 4; ++k4) {
            float4 bs = ((const float4*)bp)[k4];
            unsigned short s0 = f2bf(1.f / (1.f + __expf(-(P[k4 * 4 + 0] + bs.x))));
            unsigned short s1 = f2bf(1.f / (1.f + __expf(-(P[k4 * 4 + 1] + bs.y))));
            unsigned short s2 = f2bf(1.f / (1.f + __expf(-(P[k4 * 4 + 2] + bs.z))));
            unsigned short s3 = f2bf(1.f / (1.f + __expf(-(P[k4 * 4 + 3] + bs.w))));
            ow[k4 * 2 + 0] = (unsigned)s0 | ((unsigned)s1 << 16);
            ow[k4 * 2 + 1] = (unsigned)s2 | ((unsigned)s3 << 16);
        }
        unsigned short* op = Abf + ((size_t)b * Nn + n0 + n) * Nn + kh + kc + q * 16;
        ((uint4*)op)[0] = make_uint4(ow[0], ow[1], ow[2], ow[3]);
        ((uint4*)op)[1] = make_uint4(ow[4], ow[5], ow[6], ow[7]);
    }
}

// ---- K2b v5: faithful m201 8-phase port. BM=BN=256, BK=64, dbuf (buf0=even
// K-tile, buf1=odd). 8 waves (2m x 4n), wave out 128x64 = 8x4 16x16 frags.
// Phase = quadrant(mh,nh) x BK: {ds_read, 2 gload_lds, barrier, lgkm(0),
// sched_barrier, setprio1, 16 MFMA, setprio0, [vmcnt(6) ph3/ph7], barrier}.
// Swizzle: LDS[row][p] holds global 16B-chunk p^((row>>1)&7); inverse on src.
__global__ __launch_bounds__(512, 2) void k2b_8ph(
    const unsigned short* __restrict__ A, const unsigned short* __restrict__ Vb,
    float* __restrict__ S, unsigned* __restrict__ Mkey) {
    __shared__ __align__(16) unsigned short lds[65536];  // 2 x (A 32KB + B 32KB)

    const int tid = threadIdx.x, w = tid >> 6, lane = tid & 63;
    const int l15 = lane & 15;
    const int bid = blockIdx.x;
    const int L = ((bid & 7) << 6) + (bid >> 3);   // T1: 64 tiles/XCD, bijective
    const int i0 = (L & 3) * 256;
    const int m0 = (L >> 2) * 256;
    const int wr = w >> 2, wc = w & 3;

    // read constants: p = c ^ ((row>>1)&7); row = base16 + l15 -> s = (lane>>1)&7
    const int p0 = (lane >> 4) ^ ((lane >> 1) & 7);
    const int aBase  = (wr * 128 + l15) * 64 + p0 * 8;
    const int aBaseX = aBase ^ 32;                    // ks=1 (chunk +4)
    const int bBase  = 16384 + (wc * 64 + l15) * 64 + p0 * 8;
    const int bBaseX = bBase ^ 32;

    // stage constants: dest linear (pos = lane&7, row += lane>>3); src chunk inverse
    const int rL = lane >> 3;
    const int cS = (lane & 7) ^ ((4 * (w & 1) + (lane >> 4)) & 7);
    const int bRowW = (w >> 2) * 64 + (w & 3) * 8;
    const unsigned short* srcA00 = A  + (size_t)(m0 +   0 + 8 * w + rL) * 1024 + cS * 8;
    const unsigned short* srcA01 = A  + (size_t)(m0 + 128 + 8 * w + rL) * 1024 + cS * 8;
    const unsigned short* srcA10 = A  + (size_t)(m0 +  64 + 8 * w + rL) * 1024 + cS * 8;
    const unsigned short* srcA11 = A  + (size_t)(m0 + 192 + 8 * w + rL) * 1024 + cS * 8;
    const unsigned short* srcB00 = Vb + (size_t)(i0 +   0 + bRowW + rL) * 1024 + cS * 8;
    const unsigned short* srcB01 = Vb + (size_t)(i0 + 128 + bRowW + rL) * 1024 + cS * 8;
    const unsigned short* srcB10 = Vb + (size_t)(i0 +  32 + bRowW + rL) * 1024 + cS * 8;
    const unsigned short* srcB11 = Vb + (size_t)(i0 + 160 + bRowW + rL) * 1024 + cS * 8;
    const int dA00 = (0   + 8 * w) * 64, dA01 = (128 + 8 * w) * 64;
    const int dA10 = (64  + 8 * w) * 64, dA11 = (192 + 8 * w) * 64;
    const int dB00 = 16384 + (0   + bRowW) * 64, dB01 = 16384 + (128 + bRowW) * 64;
    const int dB10 = 16384 + (32  + bRowW) * 64, dB11 = 16384 + (160 + bRowW) * 64;

#define GLD(src, dstShorts) __builtin_amdgcn_global_load_lds(                      \
        (const __attribute__((address_space(1))) void*)(src),                     \
        (__attribute__((address_space(3))) void*)(lds + (dstShorts)), 16, 0, 0)

#define READ_A(bc, mh) do {                                                        \
    const int ro_ = (bc) * 32768 + (mh) * 4096;                                    \
    aR[0][0] = *(const bf16x8*)(lds + ro_ + aBase +    0);                         \
    aR[1][0] = *(const bf16x8*)(lds + ro_ + aBase + 1024);                         \
    aR[2][0] = *(const bf16x8*)(lds + ro_ + aBase + 2048);                         \
    aR[3][0] = *(const bf16x8*)(lds + ro_ + aBase + 3072);                         \
    aR[0][1] = *(const bf16x8*)(lds + ro_ + aBaseX +    0);                        \
    aR[1][1] = *(const bf16x8*)(lds + ro_ + aBaseX + 1024);                        \
    aR[2][1] = *(const bf16x8*)(lds + ro_ + aBaseX + 2048);                        \
    aR[3][1] = *(const bf16x8*)(lds + ro_ + aBaseX + 3072);                        \
} while (0)

#define READ_B(bc, nh, BR) do {                                                    \
    const int ro_ = (bc) * 32768 + (nh) * 2048;                                    \
    BR[0][0] = *(const bf16x8*)(lds + ro_ + bBase +    0);                         \
    BR[1][0] = *(const bf16x8*)(lds + ro_ + bBase + 1024);                         \
    BR[0][1] = *(const bf16x8*)(lds + ro_ + bBaseX +    0);                        \
    BR[1][1] = *(const bf16x8*)(lds + ro_ + bBaseX + 1024);                        \
} while (0)

#define BARRIER_LGKM                                                               \
    __builtin_amdgcn_s_barrier();                                                  \
    asm volatile("s_waitcnt lgkmcnt(0)" ::: "memory");                             \
    __builtin_amdgcn_sched_barrier(0)

#define QUAD(mh, nh, BR) do {                                                      \
    __builtin_amdgcn_s_setprio(1);                                                 \
    _Pragma("unroll")                                                              \
    for (int ks_ = 0; ks_ < 2; ++ks_)                                              \
        _Pragma("unroll")                                                          \
        for (int mi_ = 0; mi_ < 4; ++mi_)                                          \
            _Pragma("unroll")                                                      \
            for (int ni_ = 0; ni_ < 2; ++ni_)                                      \
                acc[(mh) * 4 + mi_][(nh) * 2 + ni_] =                              \
                    __builtin_amdgcn_mfma_f32_16x16x32_bf16(                       \
                        aR[mi_][ks_], BR[ni_][ks_],                                \
                        acc[(mh) * 4 + mi_][(nh) * 2 + ni_], 0, 0, 0);             \
    __builtin_amdgcn_s_setprio(0);                                                 \
} while (0)

#define VM6  asm volatile("s_waitcnt vmcnt(6)" ::: "memory")
#define ENDP __builtin_amdgcn_s_barrier()

    // ---- prologue: buf0 <- K-tile 0 (A0,B0,B1,A1), buf1 <- K-tile 1 (A0,B0,B1)
    GLD(srcA00, dA00); GLD(srcA01, dA01);
    GLD(srcB00, dB00); GLD(srcB01, dB01);
    GLD(srcB10, dB10); GLD(srcB11, dB11);
    GLD(srcA10, dA10); GLD(srcA11, dA11);
    GLD(srcA00 + 64, 32768 + dA00); GLD(srcA01 + 64, 32768 + dA01);
    GLD(srcB00 + 64, 32768 + dB00); GLD(srcB01 + 64, 32768 + dB01);
    GLD(srcB10 + 64, 32768 + dB10); GLD(srcB11 + 64, 32768 + dB11);
    asm volatile("s_waitcnt vmcnt(6)" ::: "memory");   // buf0 resident
    __builtin_amdgcn_s_barrier();

    bf16x8 aR[4][2], b0R[2][2], b1R[2][2];
    f32x4 acc[8][4] = {};

    for (int j = 0; j < 8; ++j) {
        const int k1o = (2 * j + 1) * 64;                       // always real
        const int k2o = ((j < 7) ? (2 * j + 2) : 15) * 64;      // clamp tail
        const int k3o = ((j < 7) ? (2 * j + 3) : 15) * 64;

        // ph0: buf0 quad(0,0); stage A1 -> buf1 (K-tile 2j+1)
        READ_A(0, 0); READ_B(0, 0, b0R);
        GLD(srcA10 + k1o, 32768 + dA10); GLD(srcA11 + k1o, 32768 + dA11);
        BARRIER_LGKM; QUAD(0, 0, b0R); ENDP;
        // ph1: quad(0,1); stage A0 -> buf0 (2j+2)
        READ_B(0, 1, b1R);
        GLD(srcA00 + k2o, dA00); GLD(srcA01 + k2o, dA01);
        BARRIER_LGKM; QUAD(0, 1, b1R); ENDP;
        // ph2: quad(1,0); stage B0 -> buf0
        READ_A(0, 1);
        GLD(srcB00 + k2o, dB00); GLD(srcB01 + k2o, dB01);
        BARRIER_LGKM; QUAD(1, 0, b0R); ENDP;
        // ph3: quad(1,1); stage B1 -> buf0; vmcnt(6) publishes buf1(2j+1)
        GLD(srcB10 + k2o, dB10); GLD(srcB11 + k2o, dB11);
        BARRIER_LGKM; QUAD(1, 1, b1R); VM6; ENDP;
        // ph4: buf1 quad(0,0); stage A1 -> buf0 (completes 2j+2)
        READ_A(1, 0); READ_B(1, 0, b0R);
        GLD(srcA10 + k2o, dA10); GLD(srcA11 + k2o, dA11);
        BARRIER_LGKM; QUAD(0, 0, b0R); ENDP;
        // ph5: quad(0,1); stage A0 -> buf1 (2j+3)
        READ_B(1, 1, b1R);
        GLD(srcA00 + k3o, 32768 + dA00); GLD(srcA01 + k3o, 32768 + dA01);
        BARRIER_LGKM; QUAD(0, 1, b1R); ENDP;
        // ph6: quad(1,0); stage B0 -> buf1
        READ_A(1, 1);
        GLD(srcB00 + k3o, 32768 + dB00); GLD(srcB01 + k3o, 32768 + dB01);
        BARRIER_LGKM; QUAD(1, 0, b0R); ENDP;
        // ph7: quad(1,1); stage B1 -> buf1; vmcnt(6) publishes buf0(2j+2)
        GLD(srcB10 + k3o, 32768 + dB10); GLD(srcB11 + k3o, 32768 + dB11);
        BARRIER_LGKM; QUAD(1, 1, b1R); VM6; ENDP;
    }
#undef GLD
#undef READ_A
#undef READ_B
#undef BARRIER_LGKM
#undef QUAD
#undef VM6
#undef ENDP

    // epilogue: 16x16 C/D: col = lane&15, row = (lane>>4)*4 + reg
    const int ic = i0 + wc * 64 + l15;
    const int mrb = m0 + wr * 128 + (lane >> 4) * 4;
#pragma unroll
    for (int mi8 = 0; mi8 < 8; ++mi8)
#pragma unroll
        for (int ni = 0; ni < 4; ++ni) {
            f32x4 v = acc[mi8][ni];
#pragma unroll
            for (int r = 0; r < 4; ++r)
                S[(size_t)(mrb + mi8 * 16 + r) * 1024 + ic + ni * 16] = v[r];
        }

    // fused column max over this block's 256 m-rows (single batch per tile)
    const int bcol = m0 >> 10;
#pragma unroll
    for (int ni = 0; ni < 4; ++ni) {
        float mx = -3.402823466e38f;
#pragma unroll
        for (int mi8 = 0; mi8 < 8; ++mi8)
#pragma unroll
            for (int r = 0; r < 4; ++r) mx = fmaxf(mx, acc[mi8][ni][r]);
        mx = fmaxf(mx, __shfl_xor(mx, 16));
        mx = fmaxf(mx, __shfl_xor(mx, 32));
        if ((lane >> 4) == 0)
            atomicMax(&Mkey[bcol * Nn + ic + ni * 16], fkey(mx));
    }
}

// ---- fallback fp32 fused GEMM (used only if ws too small) ----
#define KB 32
__global__ __launch_bounds__(256) void k2_gemm(
    const float* __restrict__ LHS, const float* __restrict__ RHS,
    const float* __restrict__ V_s, const float* __restrict__ b_s,
    float* __restrict__ S) {
    __shared__ float Lst[24][132];
    __shared__ float Rst[24][KB];
    __shared__ float As[KB][132];
    __shared__ float Bs[KB][132];
    int tid = threadIdx.x;
    int b = blockIdx.z;
    int n0 = blockIdx.y * 128;
    int i0 = blockIdx.x * 128;
    const float* lbase = LHS + ((size_t)b * Nn + n0) * Tt;
    for (int lin = tid; lin < 128 * Tt; lin += 256) {
        int r = lin / Tt, t = lin % Tt;
        Lst[t][r] = lbase[lin];
    }
    float acc[8][8] = {};
    int tx = tid & 15, ty = tid >> 4;
    int an = (tid & 31) * 4;
    int ak = (tid >> 5) * 4;
    const float* rbase = RHS + (size_t)b * Nn * Tt;
    for (int k0 = 0; k0 < Nn; k0 += KB) {
        __syncthreads();
        for (int lin = tid; lin < KB * Tt; lin += 256) {
            int r = lin / Tt, t = lin % Tt;
            Rst[t][r] = rbase[(size_t)(k0 + r) * Tt + t];
        }
        for (int l4 = tid; l4 < 128 * (KB / 4); l4 += 256) {
            int i = l4 >> 3, k4 = (l4 & 7) << 2;
            float4 v = *(const float4*)&V_s[(size_t)(i0 + i) * Nn + k0 + k4];
            Bs[k4 + 0][i] = v.x; Bs[k4 + 1][i] = v.y;
            Bs[k4 + 2][i] = v.z; Bs[k4 + 3][i] = v.w;
        }
        __syncthreads();
        float pacc[4][4] = {};
#pragma unroll
        for (int t = 0; t < 24; ++t) {
            float4 lv = *(const float4*)&Lst[t][an];
            float4 rv = *(const float4*)&Rst[t][ak];
            float lvv[4] = {lv.x, lv.y, lv.z, lv.w};
            float rvv[4] = {rv.x, rv.y, rv.z, rv.w};
#pragma unroll
            for (int r = 0; r < 4; ++r)
#pragma unroll
                for (int c = 0; c < 4; ++c) pacc[r][c] += lvv[r] * rvv[c];
        }
#pragma unroll
        for (int r = 0; r < 4; ++r) {
            float4 bs4 = *(const float4*)&b_s[(size_t)(n0 + an + r) * Nn + k0 + ak];
            float bsv[4] = {bs4.x, bs4.y, bs4.z, bs4.w};
#pragma unroll
            for (int c = 0; c < 4; ++c) {
                float p = pacc[r][c] + bsv[c];
                As[ak + c][an + r] = 1.f / (1.f + __expf(-p));
            }
        }
        __syncthreads();
#pragma unroll
        for (int kk = 0; kk < KB; ++kk) {
            float4 a0 = *(const float4*)&As[kk][ty * 4];
            float4 a1 = *(const float4*)&As[kk][ty * 4 + 64];
            float4 b0 = *(const float4*)&Bs[kk][tx * 4];
            float4 b1 = *(const float4*)&Bs[kk][tx * 4 + 64];
            float av[8] = {a0.x, a0.y, a0.z, a0.w, a1.x, a1.y, a1.z, a1.w};
            float bv[8] = {b0.x, b0.y, b0.z, b0.w, b1.x, b1.y, b1.z, b1.w};
#pragma unroll
            for (int r = 0; r < 8; ++r)
#pragma unroll
                for (int c = 0; c < 8; ++c) acc[r][c] += av[r] * bv[c];
        }
    }
#pragma unroll
    for (int r = 0; r < 8; ++r) {
        int nn = ty * 4 + (r & 3) + ((r >> 2) << 6);
        float4* op = (float4*)(S + ((size_t)(b * Nn + n0 + nn)) * Nn + i0 + tx * 4);
        op[0]  = make_float4(acc[r][0], acc[r][1], acc[r][2], acc[r][3]);
        op[16] = make_float4(acc[r][4], acc[r][5], acc[r][6], acc[r][7]);
    }
}

// K3: column max over n per (b,i)  (fallback path only)
__global__ __launch_bounds__(256) void k3_colmax(const float* __restrict__ S,
                                                 unsigned* __restrict__ Mkey) {
    int b = blockIdx.z;
    int i0 = blockIdx.x * 64;
    int nbase = blockIdx.y * 256;
    int ii = threadIdx.x & 63, g = threadIdx.x >> 6;
    const float* p = S + ((size_t)(b * Nn + nbase + g * 64)) * Nn + i0 + ii;
    float m = -3.402823466e38f;
#pragma unroll 4
    for (int n = 0; n < 64; ++n) m = fmaxf(m, p[(size_t)n * Nn]);
    __shared__ float red[4][64];
    red[g][ii] = m;
    __syncthreads();
    if (g == 0) {
        m = fmaxf(fmaxf(red[0][ii], red[1][ii]), fmaxf(red[2][ii], red[3][ii]));
        atomicMax(Mkey + b * Nn + i0 + ii, fkey(m));
    }
}

// K4: D0[i] = sum_n exp(S[0,n,i]-M[0,i])
__global__ __launch_bounds__(256) void k4_denom(const float* __restrict__ S,
                                                const unsigned* __restrict__ Mkey,
                                                float* __restrict__ D0) {
    int i0 = blockIdx.x * 64;
    int ii = threadIdx.x & 63, g = threadIdx.x >> 6;
    float M = keyToFloat(Mkey[i0 + ii]);
    const float* p = S + ((size_t)(g * 256)) * Nn + i0 + ii;
    float s = 0.f;
    for (int n = 0; n < 256; ++n) s += __expf(p[(size_t)n * Nn] - M);
    __shared__ float red[4][64];
    red[g][ii] = s;
    __syncthreads();
    if (g == 0) D0[i0 + ii] = (red[0][ii] + red[1][ii]) + (red[2][ii] + red[3][ii]);
}

// K5: out = exp(S - M[b,i]) / D0[i], in place
__global__ __launch_bounds__(256) void k5_final(float* __restrict__ S,
                                                const unsigned* __restrict__ Mkey,
                                                const float* __restrict__ D0) {
    const size_t total4 = (size_t)Bb * Nn * Nn / 4;
    for (size_t idx = (size_t)blockIdx.x * 256 + threadIdx.x; idx < total4;
         idx += (size_t)gridDim.x * 256) {
        size_t e = idx << 2;
        int i = (int)(e & (Nn - 1));
        int b = (int)(e >> 20);
        float4 s4 = ((const float4*)S)[idx];
        uint4 k4 = *(const uint4*)(Mkey + b * Nn + i);
        float4 d4 = *(const float4*)(D0 + i);
        float4 o;
        o.x = __expf(s4.x - keyToFloat(k4.x)) / d4.x;
        o.y = __expf(s4.y - keyToFloat(k4.y)) / d4.y;
        o.z = __expf(s4.z - keyToFloat(k4.z)) / d4.z;
        o.w = __expf(s4.w - keyToFloat(k4.w)) / d4.w;
        ((float4*)S)[idx] = o;
    }
}

extern "C" void kernel_launch(void* const* d_in, const int* in_sizes, int n_in,
                              void* d_out, int out_size, void* d_ws, size_t ws_size,
                              hipStream_t stream) {
    const float* x   = (const float*)d_in[0];
    const float* W1  = (const float*)d_in[1];
    const float* W2  = (const float*)d_in[2];
    const float* W3  = (const float*)d_in[3];
    const float* b_s = (const float*)d_in[4];
    const float* V_s = (const float*)d_in[5];
    float* out = (float*)d_out;

    char* ws = (char*)d_ws;
    float* LHS = (float*)(ws + LHS_OFF);
    float* RHS = (float*)(ws + RHS_OFF);
    unsigned* Mkey = (unsigned*)(ws + MKEY_OFF);
    float* D0 = (float*)(ws + D0_OFF);

    k1_lhs_rhs<<<Bb * Nn / 4, 256, 0, stream>>>(x, W1, W2, W3, LHS, RHS);
    hipMemsetAsync(Mkey, 0, (size_t)Bb * Nn * sizeof(unsigned), stream);

    if (ws_size >= WS_NEED) {
        unsigned short* Abf = (unsigned short*)(ws + ABF_OFF);
        unsigned short* Vb  = (unsigned short*)(ws + VB_OFF);
        k_vb<<<1024, 256, 0, stream>>>(V_s, (unsigned*)Vb);
        k2a_sig<<<dim3(16, 2, 32), 256, 0, stream>>>(LHS, RHS, b_s, Abf);
        k2b_8ph<<<512, 512, 0, stream>>>(Abf, Vb, out, Mkey);  // fused colmax
    } else {
        k2_gemm<<<dim3(Nn / 128, Nn / 128, Bb), 256, 0, stream>>>(LHS, RHS, V_s, b_s, out);
        k3_colmax<<<dim3(Nn / 64, 4, Bb), 256, 0, stream>>>(out, Mkey);
    }

    k4_denom<<<Nn / 64, 256, 0, stream>>>(out, Mkey, D0);
    k5_final<<<2048, 256, 0, stream>>>(out, Mkey, D0);
}

// Round 8
// 216.604 us; speedup vs baseline: 1.2100x; 1.1524x over previous
//
#include <hip/hip_runtime.h>
#include <hip/hip_bf16.h>

// Problem constants
#define Bb 32
#define Nn 1024
#define Ff 64
#define Tt 24

// ---- Fast-path workspace layout (bytes); ws_size measured ~768MB ----
#define LHSB_OFF 0ull                    // [32768][32] bf16 (T padded to 32) = 2MB
#define RHSB_OFF 2097152ull              // [32768][32] bf16 = 2MB
#define MKEY_OFF 4194304ull              // [32][1024] u32 colmax keys = 128KB
#define C0_OFF   4325376ull              // [1024] f32 batch-0 colsum = 4KB
#define ABF_OFF  8388608ull              // sig bf16 [32768][1024] = 64MB
#define VB_OFF   75497472ull             // V bf16 [1024][1024] = 2MB
#define E_OFF    77594624ull             // E bf16 [32768][1024] = 64MB
#define WS_NEED2 144703488ull

// ---- Fallback (old fp32 path) layout ----
#define FB_LHS_OFF  0
#define FB_RHS_OFF  3145728
#define FB_MKEY_OFF 6291456
#define FB_D0_OFF   6422528

typedef __attribute__((ext_vector_type(8))) short bf16x8;
typedef __attribute__((ext_vector_type(4))) float f32x4;

__device__ __forceinline__ unsigned fkey(float x) {
    unsigned u = __float_as_uint(x);
    return (u & 0x80000000u) ? ~u : (u | 0x80000000u);
}
__device__ __forceinline__ float keyToFloat(unsigned k) {
    unsigned u = (k & 0x80000000u) ? (k & 0x7FFFFFFFu) : ~k;
    return __uint_as_float(u);
}
__device__ __forceinline__ unsigned short f2bf(float f) {
    unsigned u = __float_as_uint(f);
    u += 0x7FFFu + ((u >> 16) & 1u);   // round-to-nearest-even
    return (unsigned short)(u >> 16);
}
__device__ __forceinline__ float bf2f(unsigned short s) {
    return __uint_as_float(((unsigned)s) << 16);
}

// ---- K1b: fused lhs/rhs -> bf16 (padded [row][32]); spare blocks convert V
// and zero Mkey/C0. One wave per (b,n) row; 4 rows/block.
__global__ __launch_bounds__(256) void k1b(
    const float* __restrict__ x, const float* __restrict__ W1,
    const float* __restrict__ W2, const float* __restrict__ W3,
    const float* __restrict__ V_s,
    unsigned short* __restrict__ LHSb, unsigned short* __restrict__ RHSb,
    unsigned* __restrict__ Vb2, unsigned* __restrict__ Mkey,
    float* __restrict__ C0) {
    __shared__ float sx[4][64][25];
    __shared__ float sy[4][64];
    __shared__ float sW1[24];
    __shared__ float sW2[64][24];
    __shared__ float sW3[64];
    __shared__ __align__(16) unsigned short pl[4][32];
    __shared__ __align__(16) unsigned short pr[4][32];
    int tid = threadIdx.x;
    if (tid < 24) sW1[tid] = W1[tid];
    if (tid < 64) sW3[tid] = W3[tid];
    for (int j = tid; j < 64 * 24; j += 256) sW2[j / 24][j % 24] = W2[j];
    __syncthreads();

    int w = tid >> 6, lane = tid & 63;
    int row = blockIdx.x * 4 + w;   // b*N+n
    const float* xr = x + (size_t)row * (Ff * Tt) + lane * Tt;
    float4 xv[6];
#pragma unroll
    for (int j = 0; j < 6; ++j) xv[j] = reinterpret_cast<const float4*>(xr)[j];
    float y = 0.f;
#pragma unroll
    for (int j = 0; j < 6; ++j) {
        y += xv[j].x * sW1[j * 4 + 0] + xv[j].y * sW1[j * 4 + 1] +
             xv[j].z * sW1[j * 4 + 2] + xv[j].w * sW1[j * 4 + 3];
    }
#pragma unroll
    for (int j = 0; j < 6; ++j) {
        sx[w][lane][j * 4 + 0] = xv[j].x;
        sx[w][lane][j * 4 + 1] = xv[j].y;
        sx[w][lane][j * 4 + 2] = xv[j].z;
        sx[w][lane][j * 4 + 3] = xv[j].w;
    }
    sy[w][lane] = y;
    __syncthreads();
    if (lane < 32) {
        if (lane < 24) {
            int t = lane;
            float la = 0.f, ra = 0.f;
#pragma unroll 8
            for (int f = 0; f < 64; ++f) {
                ra += sx[w][f][t] * sW3[f];
                la += sy[w][f] * sW2[f][t];
            }
            pl[w][t] = f2bf(la);
            pr[w][t] = f2bf(ra);
        } else {
            pl[w][lane] = 0;
            pr[w][lane] = 0;
        }
    }
    __syncthreads();
    if (lane < 4)
        ((uint4*)(LHSb + (size_t)row * 32))[lane] = ((const uint4*)pl[w])[lane];
    else if (lane < 8)
        ((uint4*)(RHSb + (size_t)row * 32))[lane - 4] = ((const uint4*)pr[w])[lane - 4];

    // extra duties
    int bid = blockIdx.x;
    if (bid < 1024) {
        size_t idx = (size_t)bid * 256 + tid;   // 256K float4 = 1M floats of V_s
        float4 v = ((const float4*)V_s)[idx];
        uint2 o;
        o.x = (unsigned)f2bf(v.x) | ((unsigned)f2bf(v.y) << 16);
        o.y = (unsigned)f2bf(v.z) | ((unsigned)f2bf(v.w) << 16);
        ((uint2*)Vb2)[idx] = o;
    } else if (bid < 1156) {
        int widx = (bid - 1024) * 256 + tid;
        if (widx < 32768) Mkey[widx] = 0u;
        else if (widx < 33792) C0[widx - 32768] = 0.f;
    }
}

// ---- k_sig: Abf[b*1024+n][k] = sigmoid(P[n][k] + b_s[n][k]) via bf16 MFMA.
// Transposed product: A = RHSb (k rows), B = LHSb (n rows), K=32 single shot.
// Block 256n x 256k, 8 waves: wave = (w>>2)*128 k-rows x (w&3)*64 n-cols.
__global__ __launch_bounds__(512) void k_sig(
    const unsigned short* __restrict__ LHSb, const unsigned short* __restrict__ RHSb,
    const float* __restrict__ b_s, unsigned short* __restrict__ Abf) {
    __shared__ __align__(16) unsigned short Rt[256 * 32];
    __shared__ __align__(16) unsigned short Lt[256 * 32];
    const int tid = threadIdx.x, w = tid >> 6, lane = tid & 63;
    const int b = blockIdx.z, n0 = blockIdx.y * 256, k0 = blockIdx.x * 256;

    // stage with swizzle: LDS[row][p] = global chunk p^((row>>1)&3)
    const int csrc = ((lane & 3) ^ ((lane >> 3) & 3)) * 8;   // ushorts
    const unsigned short* rbase = RHSb + (size_t)(b * 1024 + k0) * 32;
    const unsigned short* lbase = LHSb + (size_t)(b * 1024 + n0) * 32;
#define GLD(src, dst) __builtin_amdgcn_global_load_lds(                            \
        (const __attribute__((address_space(1))) void*)(src),                     \
        (__attribute__((address_space(3))) void*)(dst), 16, 0, 0)
    GLD(rbase + (size_t)(w * 32 + (lane >> 2)) * 32 + csrc,      Rt + (w * 32) * 32);
    GLD(rbase + (size_t)(w * 32 + 16 + (lane >> 2)) * 32 + csrc, Rt + (w * 32 + 16) * 32);
    GLD(lbase + (size_t)(w * 32 + (lane >> 2)) * 32 + csrc,      Lt + (w * 32) * 32);
    GLD(lbase + (size_t)(w * 32 + 16 + (lane >> 2)) * 32 + csrc, Lt + (w * 32 + 16) * 32);
#undef GLD
    __syncthreads();

    const int wk = (w >> 2) * 128, wn = (w & 3) * 64;
    const int l15 = lane & 15;
    const int swz8 = ((lane >> 4) ^ ((l15 >> 1) & 3)) * 8;
    bf16x8 af[8], bfr[4];
#pragma unroll
    for (int a = 0; a < 8; ++a)
        af[a] = *(const bf16x8*)(Rt + (wk + a * 16 + l15) * 32 + swz8);
#pragma unroll
    for (int c = 0; c < 4; ++c)
        bfr[c] = *(const bf16x8*)(Lt + (wn + c * 16 + l15) * 32 + swz8);

    f32x4 acc[8][4] = {};
#pragma unroll
    for (int a = 0; a < 8; ++a)
#pragma unroll
        for (int c = 0; c < 4; ++c)
            acc[a][c] = __builtin_amdgcn_mfma_f32_16x16x32_bf16(
                af[a], bfr[c], acc[a][c], 0, 0, 0);

    // epilogue: C/D col = n (l&15), row = k ((lane>>4)*4+reg)
    const int kb = k0 + wk + (lane >> 4) * 4;
    const int nb = n0 + wn + l15;
#pragma unroll
    for (int a = 0; a < 8; ++a)
#pragma unroll
        for (int c = 0; c < 4; ++c) {
            int n = nb + c * 16, k = kb + a * 16;
            float4 bs = *(const float4*)&b_s[(size_t)n * 1024 + k];
            f32x4 p = acc[a][c];
            unsigned short s0 = f2bf(1.f / (1.f + __expf(-(p[0] + bs.x))));
            unsigned short s1 = f2bf(1.f / (1.f + __expf(-(p[1] + bs.y))));
            unsigned short s2 = f2bf(1.f / (1.f + __expf(-(p[2] + bs.z))));
            unsigned short s3 = f2bf(1.f / (1.f + __expf(-(p[3] + bs.w))));
            uint2 ov;
            ov.x = (unsigned)s0 | ((unsigned)s1 << 16);
            ov.y = (unsigned)s2 | ((unsigned)s3 << 16);
            *(uint2*)(Abf + (size_t)(b * 1024 + n) * 1024 + k) = ov;
        }
}

// ---- K2b v6: round-7 8-phase core; epilogue -> E=exp(S) bf16 + colmax + b0 colsum.
__global__ __launch_bounds__(512, 2) void k2b_8ph(
    const unsigned short* __restrict__ A, const unsigned short* __restrict__ Vb,
    unsigned short* __restrict__ Ebuf, unsigned* __restrict__ Mkey,
    float* __restrict__ C0) {
    __shared__ __align__(16) unsigned short lds[65536];  // 2 x (A 32KB + B 32KB)

    const int tid = threadIdx.x, w = tid >> 6, lane = tid & 63;
    const int l15 = lane & 15;
    const int bid = blockIdx.x;
    const int L = ((bid & 7) << 6) + (bid >> 3);   // T1: 64 tiles/XCD, bijective
    const int i0 = (L & 3) * 256;
    const int m0 = (L >> 2) * 256;
    const int wr = w >> 2, wc = w & 3;

    const int p0 = (lane >> 4) ^ ((lane >> 1) & 7);
    const int aBase  = (wr * 128 + l15) * 64 + p0 * 8;
    const int aBaseX = aBase ^ 32;
    const int bBase  = 16384 + (wc * 64 + l15) * 64 + p0 * 8;
    const int bBaseX = bBase ^ 32;

    const int rL = lane >> 3;
    const int cS = (lane & 7) ^ ((4 * (w & 1) + (lane >> 4)) & 7);
    const int bRowW = (w >> 2) * 64 + (w & 3) * 8;
    const unsigned short* srcA00 = A  + (size_t)(m0 +   0 + 8 * w + rL) * 1024 + cS * 8;
    const unsigned short* srcA01 = A  + (size_t)(m0 + 128 + 8 * w + rL) * 1024 + cS * 8;
    const unsigned short* srcA10 = A  + (size_t)(m0 +  64 + 8 * w + rL) * 1024 + cS * 8;
    const unsigned short* srcA11 = A  + (size_t)(m0 + 192 + 8 * w + rL) * 1024 + cS * 8;
    const unsigned short* srcB00 = Vb + (size_t)(i0 +   0 + bRowW + rL) * 1024 + cS * 8;
    const unsigned short* srcB01 = Vb + (size_t)(i0 + 128 + bRowW + rL) * 1024 + cS * 8;
    const unsigned short* srcB10 = Vb + (size_t)(i0 +  32 + bRowW + rL) * 1024 + cS * 8;
    const unsigned short* srcB11 = Vb + (size_t)(i0 + 160 + bRowW + rL) * 1024 + cS * 8;
    const int dA00 = (0   + 8 * w) * 64, dA01 = (128 + 8 * w) * 64;
    const int dA10 = (64  + 8 * w) * 64, dA11 = (192 + 8 * w) * 64;
    const int dB00 = 16384 + (0   + bRowW) * 64, dB01 = 16384 + (128 + bRowW) * 64;
    const int dB10 = 16384 + (32  + bRowW) * 64, dB11 = 16384 + (160 + bRowW) * 64;

#define GLD(src, dstShorts) __builtin_amdgcn_global_load_lds(                      \
        (const __attribute__((address_space(1))) void*)(src),                     \
        (__attribute__((address_space(3))) void*)(lds + (dstShorts)), 16, 0, 0)

#define READ_A(bc, mh) do {                                                        \
    const int ro_ = (bc) * 32768 + (mh) * 4096;                                    \
    aR[0][0] = *(const bf16x8*)(lds + ro_ + aBase +    0);                         \
    aR[1][0] = *(const bf16x8*)(lds + ro_ + aBase + 1024);                         \
    aR[2][0] = *(const bf16x8*)(lds + ro_ + aBase + 2048);                         \
    aR[3][0] = *(const bf16x8*)(lds + ro_ + aBase + 3072);                         \
    aR[0][1] = *(const bf16x8*)(lds + ro_ + aBaseX +    0);                        \
    aR[1][1] = *(const bf16x8*)(lds + ro_ + aBaseX + 1024);                        \
    aR[2][1] = *(const bf16x8*)(lds + ro_ + aBaseX + 2048);                        \
    aR[3][1] = *(const bf16x8*)(lds + ro_ + aBaseX + 3072);                        \
} while (0)

#define READ_B(bc, nh, BR) do {                                                    \
    const int ro_ = (bc) * 32768 + (nh) * 2048;                                    \
    BR[0][0] = *(const bf16x8*)(lds + ro_ + bBase +    0);                         \
    BR[1][0] = *(const bf16x8*)(lds + ro_ + bBase + 1024);                         \
    BR[0][1] = *(const bf16x8*)(lds + ro_ + bBaseX +    0);                        \
    BR[1][1] = *(const bf16x8*)(lds + ro_ + bBaseX + 1024);                        \
} while (0)

#define BARRIER_LGKM                                                               \
    __builtin_amdgcn_s_barrier();                                                  \
    asm volatile("s_waitcnt lgkmcnt(0)" ::: "memory");                             \
    __builtin_amdgcn_sched_barrier(0)

#define QUAD(mh, nh, BR) do {                                                      \
    __builtin_amdgcn_s_setprio(1);                                                 \
    _Pragma("unroll")                                                              \
    for (int ks_ = 0; ks_ < 2; ++ks_)                                              \
        _Pragma("unroll")                                                          \
        for (int mi_ = 0; mi_ < 4; ++mi_)                                          \
            _Pragma("unroll")                                                      \
            for (int ni_ = 0; ni_ < 2; ++ni_)                                      \
                acc[(mh) * 4 + mi_][(nh) * 2 + ni_] =                              \
                    __builtin_amdgcn_mfma_f32_16x16x32_bf16(                       \
                        aR[mi_][ks_], BR[ni_][ks_],                                \
                        acc[(mh) * 4 + mi_][(nh) * 2 + ni_], 0, 0, 0);             \
    __builtin_amdgcn_s_setprio(0);                                                 \
} while (0)

#define VM6  asm volatile("s_waitcnt vmcnt(6)" ::: "memory")
#define ENDP __builtin_amdgcn_s_barrier()

    GLD(srcA00, dA00); GLD(srcA01, dA01);
    GLD(srcB00, dB00); GLD(srcB01, dB01);
    GLD(srcB10, dB10); GLD(srcB11, dB11);
    GLD(srcA10, dA10); GLD(srcA11, dA11);
    GLD(srcA00 + 64, 32768 + dA00); GLD(srcA01 + 64, 32768 + dA01);
    GLD(srcB00 + 64, 32768 + dB00); GLD(srcB01 + 64, 32768 + dB01);
    GLD(srcB10 + 64, 32768 + dB10); GLD(srcB11 + 64, 32768 + dB11);
    asm volatile("s_waitcnt vmcnt(6)" ::: "memory");
    __builtin_amdgcn_s_barrier();

    bf16x8 aR[4][2], b0R[2][2], b1R[2][2];
    f32x4 acc[8][4] = {};

    for (int j = 0; j < 8; ++j) {
        const int k1o = (2 * j + 1) * 64;
        const int k2o = ((j < 7) ? (2 * j + 2) : 15) * 64;
        const int k3o = ((j < 7) ? (2 * j + 3) : 15) * 64;

        READ_A(0, 0); READ_B(0, 0, b0R);
        GLD(srcA10 + k1o, 32768 + dA10); GLD(srcA11 + k1o, 32768 + dA11);
        BARRIER_LGKM; QUAD(0, 0, b0R); ENDP;
        READ_B(0, 1, b1R);
        GLD(srcA00 + k2o, dA00); GLD(srcA01 + k2o, dA01);
        BARRIER_LGKM; QUAD(0, 1, b1R); ENDP;
        READ_A(0, 1);
        GLD(srcB00 + k2o, dB00); GLD(srcB01 + k2o, dB01);
        BARRIER_LGKM; QUAD(1, 0, b0R); ENDP;
        GLD(srcB10 + k2o, dB10); GLD(srcB11 + k2o, dB11);
        BARRIER_LGKM; QUAD(1, 1, b1R); VM6; ENDP;
        READ_A(1, 0); READ_B(1, 0, b0R);
        GLD(srcA10 + k2o, dA10); GLD(srcA11 + k2o, dA11);
        BARRIER_LGKM; QUAD(0, 0, b0R); ENDP;
        READ_B(1, 1, b1R);
        GLD(srcA00 + k3o, 32768 + dA00); GLD(srcA01 + k3o, 32768 + dA01);
        BARRIER_LGKM; QUAD(0, 1, b1R); ENDP;
        READ_A(1, 1);
        GLD(srcB00 + k3o, 32768 + dB00); GLD(srcB01 + k3o, 32768 + dB01);
        BARRIER_LGKM; QUAD(1, 0, b0R); ENDP;
        GLD(srcB10 + k3o, 32768 + dB10); GLD(srcB11 + k3o, 32768 + dB11);
        BARRIER_LGKM; QUAD(1, 1, b1R); VM6; ENDP;
    }
#undef GLD
#undef READ_A
#undef READ_B
#undef BARRIER_LGKM
#undef QUAD
#undef VM6
#undef ENDP

    // ---- epilogue: E = exp(S); write bf16; colmax (E, monotonic); b0 colsum ----
    const int ic = i0 + wc * 64 + l15;
    const int mrb = m0 + wr * 128 + (lane >> 4) * 4;
#pragma unroll
    for (int mi8 = 0; mi8 < 8; ++mi8)
#pragma unroll
        for (int ni = 0; ni < 4; ++ni)
#pragma unroll
            for (int r = 0; r < 4; ++r)
                acc[mi8][ni][r] = __expf(acc[mi8][ni][r]);
#pragma unroll
    for (int mi8 = 0; mi8 < 8; ++mi8)
#pragma unroll
        for (int ni = 0; ni < 4; ++ni) {
            f32x4 v = acc[mi8][ni];
#pragma unroll
            for (int r = 0; r < 4; ++r)
                Ebuf[(size_t)(mrb + mi8 * 16 + r) * 1024 + ic + ni * 16] = f2bf(v[r]);
        }
    const int bcol = m0 >> 10;
#pragma unroll
    for (int ni = 0; ni < 4; ++ni) {
        float mx = 0.f, sm = 0.f;   // E > 0
#pragma unroll
        for (int mi8 = 0; mi8 < 8; ++mi8)
#pragma unroll
            for (int r = 0; r < 4; ++r) {
                float e = acc[mi8][ni][r];
                mx = fmaxf(mx, e);
                sm += e;
            }
        mx = fmaxf(mx, __shfl_xor(mx, 16));
        mx = fmaxf(mx, __shfl_xor(mx, 32));
        sm += __shfl_xor(sm, 16);
        sm += __shfl_xor(sm, 32);
        if ((lane >> 4) == 0) {
            atomicMax(&Mkey[bcol * Nn + ic + ni * 16], fkey(mx));
            if (bcol == 0) atomicAdd(&C0[ic + ni * 16], sm);
        }
    }
}

// ---- k5b: out[b,n,i] = E * ME0[i] / (ME[b,i] * C0raw[i]) ----
__global__ __launch_bounds__(256) void k5b(
    const unsigned short* __restrict__ E, const unsigned* __restrict__ Mkey,
    const float* __restrict__ C0, float* __restrict__ out) {
    const size_t total4 = (size_t)Bb * Nn * Nn / 4;   // 8,388,608
    for (size_t idx = (size_t)blockIdx.x * 256 + threadIdx.x; idx < total4;
         idx += (size_t)gridDim.x * 256) {
        size_t e4 = idx << 2;
        int i = (int)(e4 & (Nn - 1));
        int b = (int)(e4 >> 20);
        uint2 ev = ((const uint2*)E)[idx];
        uint4 mb = *(const uint4*)(Mkey + b * Nn + i);
        uint4 m0 = *(const uint4*)(Mkey + i);
        float4 c0 = *(const float4*)(C0 + i);
        float4 o;
        o.x = bf2f((unsigned short)(ev.x & 0xffffu)) *
              __fdividef(keyToFloat(m0.x), keyToFloat(mb.x) * c0.x);
        o.y = bf2f((unsigned short)(ev.x >> 16)) *
              __fdividef(keyToFloat(m0.y), keyToFloat(mb.y) * c0.y);
        o.z = bf2f((unsigned short)(ev.y & 0xffffu)) *
              __fdividef(keyToFloat(m0.z), keyToFloat(mb.z) * c0.z);
        o.w = bf2f((unsigned short)(ev.y >> 16)) *
              __fdividef(keyToFloat(m0.w), keyToFloat(mb.w) * c0.w);
        ((float4*)out)[idx] = o;
    }
}

// ======================= Fallback fp32 path (unchanged) =======================
__global__ __launch_bounds__(256) void k1_lhs_rhs(
    const float* __restrict__ x, const float* __restrict__ W1,
    const float* __restrict__ W2, const float* __restrict__ W3,
    float* __restrict__ LHS, float* __restrict__ RHS) {
    __shared__ float sx[4][64][25];
    __shared__ float sy[4][64];
    __shared__ float sW1[24];
    __shared__ float sW2[64][24];
    __shared__ float sW3[64];
    int tid = threadIdx.x;
    if (tid < 24) sW1[tid] = W1[tid];
    if (tid < 64) sW3[tid] = W3[tid];
    for (int j = tid; j < 64 * 24; j += 256) sW2[j / 24][j % 24] = W2[j];
    __syncthreads();
    int w = tid >> 6, lane = tid & 63;
    int row = blockIdx.x * 4 + w;
    const float* xr = x + (size_t)row * (Ff * Tt) + lane * Tt;
    float4 xv[6];
#pragma unroll
    for (int j = 0; j < 6; ++j) xv[j] = reinterpret_cast<const float4*>(xr)[j];
    float y = 0.f;
#pragma unroll
    for (int j = 0; j < 6; ++j) {
        y += xv[j].x * sW1[j * 4 + 0] + xv[j].y * sW1[j * 4 + 1] +
             xv[j].z * sW1[j * 4 + 2] + xv[j].w * sW1[j * 4 + 3];
    }
#pragma unroll
    for (int j = 0; j < 6; ++j) {
        sx[w][lane][j * 4 + 0] = xv[j].x;
        sx[w][lane][j * 4 + 1] = xv[j].y;
        sx[w][lane][j * 4 + 2] = xv[j].z;
        sx[w][lane][j * 4 + 3] = xv[j].w;
    }
    sy[w][lane] = y;
    __syncthreads();
    if (lane < 24) {
        int t = lane;
        float la = 0.f, ra = 0.f;
#pragma unroll 8
        for (int f = 0; f < 64; ++f) {
            ra += sx[w][f][t] * sW3[f];
            la += sy[w][f] * sW2[f][t];
        }
        LHS[(size_t)row * Tt + t] = la;
        RHS[(size_t)row * Tt + t] = ra;
    }
}

#define KB 32
__global__ __launch_bounds__(256) void k2_gemm(
    const float* __restrict__ LHS, const float* __restrict__ RHS,
    const float* __restrict__ V_s, const float* __restrict__ b_s,
    float* __restrict__ S) {
    __shared__ float Lst[24][132];
    __shared__ float Rst[24][KB];
    __shared__ float As[KB][132];
    __shared__ float Bs[KB][132];
    int tid = threadIdx.x;
    int b = blockIdx.z;
    int n0 = blockIdx.y * 128;
    int i0 = blockIdx.x * 128;
    const float* lbase = LHS + ((size_t)b * Nn + n0) * Tt;
    for (int lin = tid; lin < 128 * Tt; lin += 256) {
        int r = lin / Tt, t = lin % Tt;
        Lst[t][r] = lbase[lin];
    }
    float acc[8][8] = {};
    int tx = tid & 15, ty = tid >> 4;
    int an = (tid & 31) * 4;
    int ak = (tid >> 5) * 4;
    const float* rbase = RHS + (size_t)b * Nn * Tt;
    for (int k0 = 0; k0 < Nn; k0 += KB) {
        __syncthreads();
        for (int lin = tid; lin < KB * Tt; lin += 256) {
            int r = lin / Tt, t = lin % Tt;
            Rst[t][r] = rbase[(size_t)(k0 + r) * Tt + t];
        }
        for (int l4 = tid; l4 < 128 * (KB / 4); l4 += 256) {
            int i = l4 >> 3, k4 = (l4 & 7) << 2;
            float4 v = *(const float4*)&V_s[(size_t)(i0 + i) * Nn + k0 + k4];
            Bs[k4 + 0][i] = v.x; Bs[k4 + 1][i] = v.y;
            Bs[k4 + 2][i] = v.z; Bs[k4 + 3][i] = v.w;
        }
        __syncthreads();
        float pacc[4][4] = {};
#pragma unroll
        for (int t = 0; t < 24; ++t) {
            float4 lv = *(const float4*)&Lst[t][an];
            float4 rv = *(const float4*)&Rst[t][ak];
            float lvv[4] = {lv.x, lv.y, lv.z, lv.w};
            float rvv[4] = {rv.x, rv.y, rv.z, rv.w};
#pragma unroll
            for (int r = 0; r < 4; ++r)
#pragma unroll
                for (int c = 0; c < 4; ++c) pacc[r][c] += lvv[r] * rvv[c];
        }
#pragma unroll
        for (int r = 0; r < 4; ++r) {
            float4 bs4 = *(const float4*)&b_s[(size_t)(n0 + an + r) * Nn + k0 + ak];
            float bsv[4] = {bs4.x, bs4.y, bs4.z, bs4.w};
#pragma unroll
            for (int c = 0; c < 4; ++c) {
                float p = pacc[r][c] + bsv[c];
                As[ak + c][an + r] = 1.f / (1.f + __expf(-p));
            }
        }
        __syncthreads();
#pragma unroll
        for (int kk = 0; kk < KB; ++kk) {
            float4 a0 = *(const float4*)&As[kk][ty * 4];
            float4 a1 = *(const float4*)&As[kk][ty * 4 + 64];
            float4 b0 = *(const float4*)&Bs[kk][tx * 4];
            float4 b1 = *(const float4*)&Bs[kk][tx * 4 + 64];
            float av[8] = {a0.x, a0.y, a0.z, a0.w, a1.x, a1.y, a1.z, a1.w};
            float bv[8] = {b0.x, b0.y, b0.z, b0.w, b1.x, b1.y, b1.z, b1.w};
#pragma unroll
            for (int r = 0; r < 8; ++r)
#pragma unroll
                for (int c = 0; c < 8; ++c) acc[r][c] += av[r] * bv[c];
        }
    }
#pragma unroll
    for (int r = 0; r < 8; ++r) {
        int nn = ty * 4 + (r & 3) + ((r >> 2) << 6);
        float4* op = (float4*)(S + ((size_t)(b * Nn + n0 + nn)) * Nn + i0 + tx * 4);
        op[0]  = make_float4(acc[r][0], acc[r][1], acc[r][2], acc[r][3]);
        op[16] = make_float4(acc[r][4], acc[r][5], acc[r][6], acc[r][7]);
    }
}

__global__ __launch_bounds__(256) void k3_colmax(const float* __restrict__ S,
                                                 unsigned* __restrict__ Mkey) {
    int b = blockIdx.z;
    int i0 = blockIdx.x * 64;
    int nbase = blockIdx.y * 256;
    int ii = threadIdx.x & 63, g = threadIdx.x >> 6;
    const float* p = S + ((size_t)(b * Nn + nbase + g * 64)) * Nn + i0 + ii;
    float m = -3.402823466e38f;
#pragma unroll 4
    for (int n = 0; n < 64; ++n) m = fmaxf(m, p[(size_t)n * Nn]);
    __shared__ float red[4][64];
    red[g][ii] = m;
    __syncthreads();
    if (g == 0) {
        m = fmaxf(fmaxf(red[0][ii], red[1][ii]), fmaxf(red[2][ii], red[3][ii]));
        atomicMax(Mkey + b * Nn + i0 + ii, fkey(m));
    }
}

__global__ __launch_bounds__(256) void k4_denom(const float* __restrict__ S,
                                                const unsigned* __restrict__ Mkey,
                                                float* __restrict__ D0) {
    int i0 = blockIdx.x * 64;
    int ii = threadIdx.x & 63, g = threadIdx.x >> 6;
    float M = keyToFloat(Mkey[i0 + ii]);
    const float* p = S + ((size_t)(g * 256)) * Nn + i0 + ii;
    float s = 0.f;
    for (int n = 0; n < 256; ++n) s += __expf(p[(size_t)n * Nn] - M);
    __shared__ float red[4][64];
    red[g][ii] = s;
    __syncthreads();
    if (g == 0) D0[i0 + ii] = (red[0][ii] + red[1][ii]) + (red[2][ii] + red[3][ii]);
}

__global__ __launch_bounds__(256) void k5_final(float* __restrict__ S,
                                                const unsigned* __restrict__ Mkey,
                                                const float* __restrict__ D0) {
    const size_t total4 = (size_t)Bb * Nn * Nn / 4;
    for (size_t idx = (size_t)blockIdx.x * 256 + threadIdx.x; idx < total4;
         idx += (size_t)gridDim.x * 256) {
        size_t e = idx << 2;
        int i = (int)(e & (Nn - 1));
        int b = (int)(e >> 20);
        float4 s4 = ((const float4*)S)[idx];
        uint4 k4 = *(const uint4*)(Mkey + b * Nn + i);
        float4 d4 = *(const float4*)(D0 + i);
        float4 o;
        o.x = __expf(s4.x - keyToFloat(k4.x)) / d4.x;
        o.y = __expf(s4.y - keyToFloat(k4.y)) / d4.y;
        o.z = __expf(s4.z - keyToFloat(k4.z)) / d4.z;
        o.w = __expf(s4.w - keyToFloat(k4.w)) / d4.w;
        ((float4*)S)[idx] = o;
    }
}

extern "C" void kernel_launch(void* const* d_in, const int* in_sizes, int n_in,
                              void* d_out, int out_size, void* d_ws, size_t ws_size,
                              hipStream_t stream) {
    const float* x   = (const float*)d_in[0];
    const float* W1  = (const float*)d_in[1];
    const float* W2  = (const float*)d_in[2];
    const float* W3  = (const float*)d_in[3];
    const float* b_s = (const float*)d_in[4];
    const float* V_s = (const float*)d_in[5];
    float* out = (float*)d_out;
    char* ws = (char*)d_ws;

    if (ws_size >= WS_NEED2) {
        unsigned short* LHSb = (unsigned short*)(ws + LHSB_OFF);
        unsigned short* RHSb = (unsigned short*)(ws + RHSB_OFF);
        unsigned* Mkey = (unsigned*)(ws + MKEY_OFF);
        float* C0 = (float*)(ws + C0_OFF);
        unsigned short* Abf = (unsigned short*)(ws + ABF_OFF);
        unsigned short* Vb  = (unsigned short*)(ws + VB_OFF);
        unsigned short* Eb  = (unsigned short*)(ws + E_OFF);

        k1b<<<Bb * Nn / 4, 256, 0, stream>>>(x, W1, W2, W3, V_s, LHSb, RHSb,
                                             (unsigned*)Vb, Mkey, C0);
        k_sig<<<dim3(4, 4, Bb), 512, 0, stream>>>(LHSb, RHSb, b_s, Abf);
        k2b_8ph<<<512, 512, 0, stream>>>(Abf, Vb, Eb, Mkey, C0);
        k5b<<<2048, 256, 0, stream>>>(Eb, Mkey, C0, out);
    } else {
        float* LHS = (float*)(ws + FB_LHS_OFF);
        float* RHS = (float*)(ws + FB_RHS_OFF);
        unsigned* Mkey = (unsigned*)(ws + FB_MKEY_OFF);
        float* D0 = (float*)(ws + FB_D0_OFF);
        k1_lhs_rhs<<<Bb * Nn / 4, 256, 0, stream>>>(x, W1, W2, W3, LHS, RHS);
        hipMemsetAsync(Mkey, 0, (size_t)Bb * Nn * sizeof(unsigned), stream);
        k2_gemm<<<dim3(Nn / 128, Nn / 128, Bb), 256, 0, stream>>>(LHS, RHS, V_s, b_s, out);
        k3_colmax<<<dim3(Nn / 64, 4, Bb), 256, 0, stream>>>(out, Mkey);
        k4_denom<<<Nn / 64, 256, 0, stream>>>(out, Mkey, D0);
        k5_final<<<2048, 256, 0, stream>>>(out, Mkey, D0);
    }
}

// Round 9
// 215.662 us; speedup vs baseline: 1.2153x; 1.0044x over previous
//
#include <hip/hip_runtime.h>
#include <hip/hip_bf16.h>

// Problem constants
#define Bb 32
#define Nn 1024
#define Ff 64
#define Tt 24

// ---- Fast-path workspace layout (bytes); ws_size measured ~768MB ----
#define LHSB_OFF 0ull                    // [32768][32] bf16 (T padded to 32) = 2MB
#define RHSB_OFF 2097152ull              // [32768][32] bf16 = 2MB
#define MKEY_OFF 4194304ull              // [32][1024] u32 colmax keys = 128KB
#define C0_OFF   4325376ull              // [1024] f32 batch-0 colsum = 4KB
#define ABF_OFF  8388608ull              // sig bf16 [32768][1024] = 64MB
#define VB_OFF   75497472ull             // V bf16 [1024][1024] = 2MB
#define E_OFF    77594624ull             // E bf16 [32768][1024] = 64MB
#define WS_NEED2 144703488ull

// ---- Fallback (old fp32 path) layout ----
#define FB_LHS_OFF  0
#define FB_RHS_OFF  3145728
#define FB_MKEY_OFF 6291456
#define FB_D0_OFF   6422528

typedef __attribute__((ext_vector_type(8))) short bf16x8;
typedef __attribute__((ext_vector_type(4))) float f32x4;
typedef __attribute__((ext_vector_type(16))) float f32x16;

__device__ __forceinline__ unsigned fkey(float x) {
    unsigned u = __float_as_uint(x);
    return (u & 0x80000000u) ? ~u : (u | 0x80000000u);
}
__device__ __forceinline__ float keyToFloat(unsigned k) {
    unsigned u = (k & 0x80000000u) ? (k & 0x7FFFFFFFu) : ~k;
    return __uint_as_float(u);
}
__device__ __forceinline__ unsigned short f2bf(float f) {
    unsigned u = __float_as_uint(f);
    u += 0x7FFFu + ((u >> 16) & 1u);   // round-to-nearest-even
    return (unsigned short)(u >> 16);
}
__device__ __forceinline__ float bf2f(unsigned short s) {
    return __uint_as_float(((unsigned)s) << 16);
}

// ---- K1b: fused lhs/rhs -> bf16 (padded [row][32]); spare duties: V->bf16,
// zero Mkey/C0. One wave per (b,n) row; 4 rows/block.
__global__ __launch_bounds__(256) void k1b(
    const float* __restrict__ x, const float* __restrict__ W1,
    const float* __restrict__ W2, const float* __restrict__ W3,
    const float* __restrict__ V_s,
    unsigned short* __restrict__ LHSb, unsigned short* __restrict__ RHSb,
    unsigned* __restrict__ Vb2, unsigned* __restrict__ Mkey,
    float* __restrict__ C0) {
    __shared__ float sx[4][64][25];
    __shared__ float sy[4][64];
    __shared__ float sW1[24];
    __shared__ float sW2[64][24];
    __shared__ float sW3[64];
    __shared__ __align__(16) unsigned short pl[4][32];
    __shared__ __align__(16) unsigned short pr[4][32];
    int tid = threadIdx.x;
    if (tid < 24) sW1[tid] = W1[tid];
    if (tid < 64) sW3[tid] = W3[tid];
    for (int j = tid; j < 64 * 24; j += 256) sW2[j / 24][j % 24] = W2[j];
    __syncthreads();

    int w = tid >> 6, lane = tid & 63;
    int row = blockIdx.x * 4 + w;   // b*N+n
    const float* xr = x + (size_t)row * (Ff * Tt) + lane * Tt;
    float4 xv[6];
#pragma unroll
    for (int j = 0; j < 6; ++j) xv[j] = reinterpret_cast<const float4*>(xr)[j];
    float y = 0.f;
#pragma unroll
    for (int j = 0; j < 6; ++j) {
        y += xv[j].x * sW1[j * 4 + 0] + xv[j].y * sW1[j * 4 + 1] +
             xv[j].z * sW1[j * 4 + 2] + xv[j].w * sW1[j * 4 + 3];
    }
#pragma unroll
    for (int j = 0; j < 6; ++j) {
        sx[w][lane][j * 4 + 0] = xv[j].x;
        sx[w][lane][j * 4 + 1] = xv[j].y;
        sx[w][lane][j * 4 + 2] = xv[j].z;
        sx[w][lane][j * 4 + 3] = xv[j].w;
    }
    sy[w][lane] = y;
    __syncthreads();
    if (lane < 32) {
        if (lane < 24) {
            int t = lane;
            float la = 0.f, ra = 0.f;
#pragma unroll 8
            for (int f = 0; f < 64; ++f) {
                ra += sx[w][f][t] * sW3[f];
                la += sy[w][f] * sW2[f][t];
            }
            pl[w][t] = f2bf(la);
            pr[w][t] = f2bf(ra);
        } else {
            pl[w][lane] = 0;
            pr[w][lane] = 0;
        }
    }
    __syncthreads();
    if (lane < 4)
        ((uint4*)(LHSb + (size_t)row * 32))[lane] = ((const uint4*)pl[w])[lane];
    else if (lane < 8)
        ((uint4*)(RHSb + (size_t)row * 32))[lane - 4] = ((const uint4*)pr[w])[lane - 4];

    // extra duties
    int bid = blockIdx.x;
    if (bid < 1024) {
        size_t idx = (size_t)bid * 256 + tid;   // 256K float4 = 1M floats of V_s
        float4 v = ((const float4*)V_s)[idx];
        uint2 o;
        o.x = (unsigned)f2bf(v.x) | ((unsigned)f2bf(v.y) << 16);
        o.y = (unsigned)f2bf(v.z) | ((unsigned)f2bf(v.w) << 16);
        ((uint2*)Vb2)[idx] = o;
    } else if (bid < 1156) {
        int widx = (bid - 1024) * 256 + tid;
        if (widx < 32768) Mkey[widx] = 0u;
        else if (widx < 33792) C0[widx - 32768] = 0.f;
    }
}

// ---- k_sig v2: Abf[b*1024+n][k] = sigmoid(P[n][k]+b_s[n][k]) via bf16 MFMA,
// with per-wave LDS bounce for fully-coalesced 64MB writes.
// Block 256n x 256k, 8 waves: wave = (w>>2)*128 k-rows x (w&3)*64 n-cols.
__global__ __launch_bounds__(512) void k_sig(
    const unsigned short* __restrict__ LHSb, const unsigned short* __restrict__ RHSb,
    const float* __restrict__ b_s, unsigned short* __restrict__ Abf) {
    // phase 1: Rt = sbuf[0..8191], Lt = sbuf[8192..16383] (256x32 each)
    // phase 2 (after sync): per-wave bounce [16][136] at w*2176
    __shared__ __align__(16) unsigned short sbuf[17408];
    unsigned short* Rt = sbuf;
    unsigned short* Lt = sbuf + 8192;
    const int tid = threadIdx.x, w = tid >> 6, lane = tid & 63;
    const int b = blockIdx.z, n0 = blockIdx.y * 256, k0 = blockIdx.x * 256;

    // stage with swizzle: LDS[row][p] = global chunk p^((row>>1)&3)
    const int csrc = ((lane & 3) ^ ((lane >> 3) & 3)) * 8;   // ushorts
    const unsigned short* rbase = RHSb + (size_t)(b * 1024 + k0) * 32;
    const unsigned short* lbase = LHSb + (size_t)(b * 1024 + n0) * 32;
#define GLD(src, dst) __builtin_amdgcn_global_load_lds(                            \
        (const __attribute__((address_space(1))) void*)(src),                     \
        (__attribute__((address_space(3))) void*)(dst), 16, 0, 0)
    GLD(rbase + (size_t)(w * 32 + (lane >> 2)) * 32 + csrc,      Rt + (w * 32) * 32);
    GLD(rbase + (size_t)(w * 32 + 16 + (lane >> 2)) * 32 + csrc, Rt + (w * 32 + 16) * 32);
    GLD(lbase + (size_t)(w * 32 + (lane >> 2)) * 32 + csrc,      Lt + (w * 32) * 32);
    GLD(lbase + (size_t)(w * 32 + 16 + (lane >> 2)) * 32 + csrc, Lt + (w * 32 + 16) * 32);
#undef GLD
    __syncthreads();

    const int wk = (w >> 2) * 128, wn = (w & 3) * 64;
    const int l15 = lane & 15;
    const int swz8 = ((lane >> 4) ^ ((l15 >> 1) & 3)) * 8;
    bf16x8 af[8], bfr[4];
#pragma unroll
    for (int a = 0; a < 8; ++a)
        af[a] = *(const bf16x8*)(Rt + (wk + a * 16 + l15) * 32 + swz8);
#pragma unroll
    for (int c = 0; c < 4; ++c)
        bfr[c] = *(const bf16x8*)(Lt + (wn + c * 16 + l15) * 32 + swz8);

    f32x4 acc[8][4] = {};
#pragma unroll
    for (int a = 0; a < 8; ++a)
#pragma unroll
        for (int c = 0; c < 4; ++c)
            acc[a][c] = __builtin_amdgcn_mfma_f32_16x16x32_bf16(
                af[a], bfr[c], acc[a][c], 0, 0, 0);

    __syncthreads();   // all staging reads done; sbuf reusable as bounce

    // C/D: col = n (l15), row = k = 4*(lane>>4)+reg. Regs = 4 consecutive k.
    unsigned short* Bw = sbuf + w * 2176;   // [16][136] padded, 16B-aligned rows
    const int h = lane >> 4;                // 0..3
#pragma unroll
    for (int c = 0; c < 4; ++c) {
        int n = n0 + wn + c * 16 + l15;
        const float* bsrow = b_s + (size_t)n * 1024 + k0 + wk;
#pragma unroll
        for (int a = 0; a < 8; ++a) {
            int kloc = a * 16 + h * 4;
            float4 bs = *(const float4*)(bsrow + kloc);
            f32x4 p = acc[a][c];
            unsigned short s0 = f2bf(1.f / (1.f + __expf(-(p[0] + bs.x))));
            unsigned short s1 = f2bf(1.f / (1.f + __expf(-(p[1] + bs.y))));
            unsigned short s2 = f2bf(1.f / (1.f + __expf(-(p[2] + bs.z))));
            unsigned short s3 = f2bf(1.f / (1.f + __expf(-(p[3] + bs.w))));
            uint2 pk;
            pk.x = (unsigned)s0 | ((unsigned)s1 << 16);
            pk.y = (unsigned)s2 | ((unsigned)s3 << 16);
            *(uint2*)(Bw + l15 * 136 + kloc) = pk;
        }
        asm volatile("s_waitcnt lgkmcnt(0)" ::: "memory");   // wave-private bounce
        // read rows out, store coalesced (1KB per instr: 4 rows x 256B)
#pragma unroll
        for (int q = 0; q < 4; ++q) {
            int r = q * 4 + h;
            uint4 v = *(const uint4*)(Bw + r * 136 + l15 * 8);
            int nn = n0 + wn + c * 16 + r;
            *(uint4*)(Abf + (size_t)(b * 1024 + nn) * 1024 + k0 + wk + l15 * 8) = v;
        }
    }
}

// ---- K2b v7: m201 8-phase schedule (unchanged) + 32x32x16 MFMA fragments.
// Epilogue -> E=exp(S) bf16 + colmax + batch-0 colsum.
__global__ __launch_bounds__(512, 2) void k2b_8ph(
    const unsigned short* __restrict__ A, const unsigned short* __restrict__ Vb,
    unsigned short* __restrict__ Ebuf, unsigned* __restrict__ Mkey,
    float* __restrict__ C0) {
    __shared__ __align__(16) unsigned short lds[65536];  // 2 x (A 32KB + B 32KB)

    const int tid = threadIdx.x, w = tid >> 6, lane = tid & 63;
    const int bid = blockIdx.x;
    const int L = ((bid & 7) << 6) + (bid >> 3);   // T1: 64 tiles/XCD, bijective
    const int i0 = (L & 3) * 256;
    const int m0 = (L >> 2) * 256;
    const int wr = w >> 2, wc = w & 3;

    // ---- 32x32 read constants: LDS[row][p] = chunk p^((row>>1)&7) ----
    const int lane31 = lane & 31;
    const int half8 = lane >> 5;                       // 0/1
    const int swz = (lane >> 1) & 7;                   // = (lane31>>1)&7
    const int aB32 = (wr * 128 + lane31) * 64;         // + mh*4096 + f*2048
    const int bB32 = 16384 + (wc * 64 + lane31) * 64;  // + nh*2048
    int c32[4];
#pragma unroll
    for (int s = 0; s < 4; ++s) c32[s] = ((2 * s + half8) ^ swz) * 8;

    // ---- staging constants (identical to round 7/8) ----
    const int rL = lane >> 3;
    const int cS = (lane & 7) ^ ((4 * (w & 1) + (lane >> 4)) & 7);
    const int bRowW = (w >> 2) * 64 + (w & 3) * 8;
    const unsigned short* srcA00 = A  + (size_t)(m0 +   0 + 8 * w + rL) * 1024 + cS * 8;
    const unsigned short* srcA01 = A  + (size_t)(m0 + 128 + 8 * w + rL) * 1024 + cS * 8;
    const unsigned short* srcA10 = A  + (size_t)(m0 +  64 + 8 * w + rL) * 1024 + cS * 8;
    const unsigned short* srcA11 = A  + (size_t)(m0 + 192 + 8 * w + rL) * 1024 + cS * 8;
    const unsigned short* srcB00 = Vb + (size_t)(i0 +   0 + bRowW + rL) * 1024 + cS * 8;
    const unsigned short* srcB01 = Vb + (size_t)(i0 + 128 + bRowW + rL) * 1024 + cS * 8;
    const unsigned short* srcB10 = Vb + (size_t)(i0 +  32 + bRowW + rL) * 1024 + cS * 8;
    const unsigned short* srcB11 = Vb + (size_t)(i0 + 160 + bRowW + rL) * 1024 + cS * 8;
    const int dA00 = (0   + 8 * w) * 64, dA01 = (128 + 8 * w) * 64;
    const int dA10 = (64  + 8 * w) * 64, dA11 = (192 + 8 * w) * 64;
    const int dB00 = 16384 + (0   + bRowW) * 64, dB01 = 16384 + (128 + bRowW) * 64;
    const int dB10 = 16384 + (32  + bRowW) * 64, dB11 = 16384 + (160 + bRowW) * 64;

#define GLD(src, dstShorts) __builtin_amdgcn_global_load_lds(                      \
        (const __attribute__((address_space(1))) void*)(src),                     \
        (__attribute__((address_space(3))) void*)(lds + (dstShorts)), 16, 0, 0)

#define READ_A32(bc, mh) do {                                                      \
    const int ro_ = (bc) * 32768 + (mh) * 4096;                                    \
    _Pragma("unroll")                                                              \
    for (int f_ = 0; f_ < 2; ++f_)                                                 \
        _Pragma("unroll")                                                          \
        for (int s_ = 0; s_ < 4; ++s_)                                             \
            aR[f_][s_] = *(const bf16x8*)(lds + ro_ + aB32 + f_ * 2048 + c32[s_]); \
} while (0)

#define READ_B32(bc, nh, BR) do {                                                  \
    const int ro_ = (bc) * 32768 + (nh) * 2048;                                    \
    _Pragma("unroll")                                                              \
    for (int s_ = 0; s_ < 4; ++s_)                                                 \
        BR[s_] = *(const bf16x8*)(lds + ro_ + bB32 + c32[s_]);                     \
} while (0)

#define BARRIER_LGKM                                                               \
    __builtin_amdgcn_s_barrier();                                                  \
    asm volatile("s_waitcnt lgkmcnt(0)" ::: "memory");                             \
    __builtin_amdgcn_sched_barrier(0)

#define QUAD32(mh, nh, BR) do {                                                    \
    __builtin_amdgcn_s_setprio(1);                                                 \
    _Pragma("unroll")                                                              \
    for (int s_ = 0; s_ < 4; ++s_)                                                 \
        _Pragma("unroll")                                                          \
        for (int f_ = 0; f_ < 2; ++f_)                                             \
            acc[(mh) * 2 + f_][nh] = __builtin_amdgcn_mfma_f32_32x32x16_bf16(      \
                aR[f_][s_], BR[s_], acc[(mh) * 2 + f_][nh], 0, 0, 0);              \
    __builtin_amdgcn_s_setprio(0);                                                 \
} while (0)

#define LGKM8 asm volatile("s_waitcnt lgkmcnt(8)" ::: "memory")
#define VM6   asm volatile("s_waitcnt vmcnt(6)" ::: "memory")
#define ENDP  __builtin_amdgcn_s_barrier()

    // ---- prologue: buf0 <- K-tile 0, buf1 <- K-tile 1 (A0,B0,B1) ----
    GLD(srcA00, dA00); GLD(srcA01, dA01);
    GLD(srcB00, dB00); GLD(srcB01, dB01);
    GLD(srcB10, dB10); GLD(srcB11, dB11);
    GLD(srcA10, dA10); GLD(srcA11, dA11);
    GLD(srcA00 + 64, 32768 + dA00); GLD(srcA01 + 64, 32768 + dA01);
    GLD(srcB00 + 64, 32768 + dB00); GLD(srcB01 + 64, 32768 + dB01);
    GLD(srcB10 + 64, 32768 + dB10); GLD(srcB11 + 64, 32768 + dB11);
    asm volatile("s_waitcnt vmcnt(6)" ::: "memory");
    __builtin_amdgcn_s_barrier();

    bf16x8 aR[2][4], b0R[4], b1R[4];
    f32x16 acc[4][2] = {};

    for (int j = 0; j < 8; ++j) {
        const int k1o = (2 * j + 1) * 64;
        const int k2o = ((j < 7) ? (2 * j + 2) : 15) * 64;
        const int k3o = ((j < 7) ? (2 * j + 3) : 15) * 64;

        // ph0: buf0 quad(0,0); stage A1 -> buf1 (K-tile 2j+1)
        READ_A32(0, 0); READ_B32(0, 0, b0R);
        GLD(srcA10 + k1o, 32768 + dA10); GLD(srcA11 + k1o, 32768 + dA11);
        LGKM8;
        BARRIER_LGKM; QUAD32(0, 0, b0R); ENDP;
        // ph1: quad(0,1); stage A0 -> buf0 (2j+2)
        READ_B32(0, 1, b1R);
        GLD(srcA00 + k2o, dA00); GLD(srcA01 + k2o, dA01);
        BARRIER_LGKM; QUAD32(0, 1, b1R); ENDP;
        // ph2: quad(1,0); stage B0 -> buf0
        READ_A32(0, 1);
        GLD(srcB00 + k2o, dB00); GLD(srcB01 + k2o, dB01);
        BARRIER_LGKM; QUAD32(1, 0, b0R); ENDP;
        // ph3: quad(1,1); stage B1 -> buf0; vmcnt(6) publishes buf1(2j+1)
        GLD(srcB10 + k2o, dB10); GLD(srcB11 + k2o, dB11);
        BARRIER_LGKM; QUAD32(1, 1, b1R); VM6; ENDP;
        // ph4: buf1 quad(0,0); stage A1 -> buf0 (completes 2j+2)
        READ_A32(1, 0); READ_B32(1, 0, b0R);
        GLD(srcA10 + k2o, dA10); GLD(srcA11 + k2o, dA11);
        LGKM8;
        BARRIER_LGKM; QUAD32(0, 0, b0R); ENDP;
        // ph5: quad(0,1); stage A0 -> buf1 (2j+3)
        READ_B32(1, 1, b1R);
        GLD(srcA00 + k3o, 32768 + dA00); GLD(srcA01 + k3o, 32768 + dA01);
        BARRIER_LGKM; QUAD32(0, 1, b1R); ENDP;
        // ph6: quad(1,0); stage B0 -> buf1
        READ_A32(1, 1);
        GLD(srcB00 + k3o, 32768 + dB00); GLD(srcB01 + k3o, 32768 + dB01);
        BARRIER_LGKM; QUAD32(1, 0, b0R); ENDP;
        // ph7: quad(1,1); stage B1 -> buf1; vmcnt(6) publishes buf0(2j+2)
        GLD(srcB10 + k3o, 32768 + dB10); GLD(srcB11 + k3o, 32768 + dB11);
        BARRIER_LGKM; QUAD32(1, 1, b1R); VM6; ENDP;
    }
#undef GLD
#undef READ_A32
#undef READ_B32
#undef BARRIER_LGKM
#undef QUAD32
#undef LGKM8
#undef VM6
#undef ENDP

    // ---- epilogue: 32x32 C/D: col = lane31, row = 4*half8 + (reg&3)+8*(reg>>2)
    const int colD = i0 + wc * 64 + lane31;
    const int rowD = m0 + wr * 128 + 4 * half8;
#pragma unroll
    for (int rf = 0; rf < 4; ++rf)
#pragma unroll
        for (int cf = 0; cf < 2; ++cf)
#pragma unroll
            for (int reg = 0; reg < 16; ++reg)
                acc[rf][cf][reg] = __expf(acc[rf][cf][reg]);
#pragma unroll
    for (int rf = 0; rf < 4; ++rf)
#pragma unroll
        for (int cf = 0; cf < 2; ++cf)
#pragma unroll
            for (int reg = 0; reg < 16; ++reg) {
                int r = rowD + rf * 32 + (reg & 3) + 8 * (reg >> 2);
                Ebuf[(size_t)r * 1024 + colD + cf * 32] = f2bf(acc[rf][cf][reg]);
            }
    const int bcol = m0 >> 10;
#pragma unroll
    for (int cf = 0; cf < 2; ++cf) {
        float mx = 0.f, sm = 0.f;   // E > 0
#pragma unroll
        for (int rf = 0; rf < 4; ++rf)
#pragma unroll
            for (int reg = 0; reg < 16; ++reg) {
                float e = acc[rf][cf][reg];
                mx = fmaxf(mx, e);
                sm += e;
            }
        mx = fmaxf(mx, __shfl_xor(mx, 32));
        sm += __shfl_xor(sm, 32);
        if (lane < 32) {
            atomicMax(&Mkey[bcol * Nn + colD + cf * 32], fkey(mx));
            if (bcol == 0) atomicAdd(&C0[colD + cf * 32], sm);
        }
    }
}

// ---- k5b: out[b,n,i] = E * ME0[i] / (ME[b,i] * C0raw[i]) ----
__global__ __launch_bounds__(256) void k5b(
    const unsigned short* __restrict__ E, const unsigned* __restrict__ Mkey,
    const float* __restrict__ C0, float* __restrict__ out) {
    const size_t total4 = (size_t)Bb * Nn * Nn / 4;   // 8,388,608
    for (size_t idx = (size_t)blockIdx.x * 256 + threadIdx.x; idx < total4;
         idx += (size_t)gridDim.x * 256) {
        size_t e4 = idx << 2;
        int i = (int)(e4 & (Nn - 1));
        int b = (int)(e4 >> 20);
        uint2 ev = ((const uint2*)E)[idx];
        uint4 mb = *(const uint4*)(Mkey + b * Nn + i);
        uint4 m0 = *(const uint4*)(Mkey + i);
        float4 c0 = *(const float4*)(C0 + i);
        float4 o;
        o.x = bf2f((unsigned short)(ev.x & 0xffffu)) *
              __fdividef(keyToFloat(m0.x), keyToFloat(mb.x) * c0.x);
        o.y = bf2f((unsigned short)(ev.x >> 16)) *
              __fdividef(keyToFloat(m0.y), keyToFloat(mb.y) * c0.y);
        o.z = bf2f((unsigned short)(ev.y & 0xffffu)) *
              __fdividef(keyToFloat(m0.z), keyToFloat(mb.z) * c0.z);
        o.w = bf2f((unsigned short)(ev.y >> 16)) *
              __fdividef(keyToFloat(m0.w), keyToFloat(mb.w) * c0.w);
        ((float4*)out)[idx] = o;
    }
}

// ======================= Fallback fp32 path (unchanged) =======================
__global__ __launch_bounds__(256) void k1_lhs_rhs(
    const float* __restrict__ x, const float* __restrict__ W1,
    const float* __restrict__ W2, const float* __restrict__ W3,
    float* __restrict__ LHS, float* __restrict__ RHS) {
    __shared__ float sx[4][64][25];
    __shared__ float sy[4][64];
    __shared__ float sW1[24];
    __shared__ float sW2[64][24];
    __shared__ float sW3[64];
    int tid = threadIdx.x;
    if (tid < 24) sW1[tid] = W1[tid];
    if (tid < 64) sW3[tid] = W3[tid];
    for (int j = tid; j < 64 * 24; j += 256) sW2[j / 24][j % 24] = W2[j];
    __syncthreads();
    int w = tid >> 6, lane = tid & 63;
    int row = blockIdx.x * 4 + w;
    const float* xr = x + (size_t)row * (Ff * Tt) + lane * Tt;
    float4 xv[6];
#pragma unroll
    for (int j = 0; j < 6; ++j) xv[j] = reinterpret_cast<const float4*>(xr)[j];
    float y = 0.f;
#pragma unroll
    for (int j = 0; j < 6; ++j) {
        y += xv[j].x * sW1[j * 4 + 0] + xv[j].y * sW1[j * 4 + 1] +
             xv[j].z * sW1[j * 4 + 2] + xv[j].w * sW1[j * 4 + 3];
    }
#pragma unroll
    for (int j = 0; j < 6; ++j) {
        sx[w][lane][j * 4 + 0] = xv[j].x;
        sx[w][lane][j * 4 + 1] = xv[j].y;
        sx[w][lane][j * 4 + 2] = xv[j].z;
        sx[w][lane][j * 4 + 3] = xv[j].w;
    }
    sy[w][lane] = y;
    __syncthreads();
    if (lane < 24) {
        int t = lane;
        float la = 0.f, ra = 0.f;
#pragma unroll 8
        for (int f = 0; f < 64; ++f) {
            ra += sx[w][f][t] * sW3[f];
            la += sy[w][f] * sW2[f][t];
        }
        LHS[(size_t)row * Tt + t] = la;
        RHS[(size_t)row * Tt + t] = ra;
    }
}

#define KB 32
__global__ __launch_bounds__(256) void k2_gemm(
    const float* __restrict__ LHS, const float* __restrict__ RHS,
    const float* __restrict__ V_s, const float* __restrict__ b_s,
    float* __restrict__ S) {
    __shared__ float Lst[24][132];
    __shared__ float Rst[24][KB];
    __shared__ float As[KB][132];
    __shared__ float Bs[KB][132];
    int tid = threadIdx.x;
    int b = blockIdx.z;
    int n0 = blockIdx.y * 128;
    int i0 = blockIdx.x * 128;
    const float* lbase = LHS + ((size_t)b * Nn + n0) * Tt;
    for (int lin = tid; lin < 128 * Tt; lin += 256) {
        int r = lin / Tt, t = lin % Tt;
        Lst[t][r] = lbase[lin];
    }
    float acc[8][8] = {};
    int tx = tid & 15, ty = tid >> 4;
    int an = (tid & 31) * 4;
    int ak = (tid >> 5) * 4;
    const float* rbase = RHS + (size_t)b * Nn * Tt;
    for (int k0 = 0; k0 < Nn; k0 += KB) {
        __syncthreads();
        for (int lin = tid; lin < KB * Tt; lin += 256) {
            int r = lin / Tt, t = lin % Tt;
            Rst[t][r] = rbase[(size_t)(k0 + r) * Tt + t];
        }
        for (int l4 = tid; l4 < 128 * (KB / 4); l4 += 256) {
            int i = l4 >> 3, k4 = (l4 & 7) << 2;
            float4 v = *(const float4*)&V_s[(size_t)(i0 + i) * Nn + k0 + k4];
            Bs[k4 + 0][i] = v.x; Bs[k4 + 1][i] = v.y;
            Bs[k4 + 2][i] = v.z; Bs[k4 + 3][i] = v.w;
        }
        __syncthreads();
        float pacc[4][4] = {};
#pragma unroll
        for (int t = 0; t < 24; ++t) {
            float4 lv = *(const float4*)&Lst[t][an];
            float4 rv = *(const float4*)&Rst[t][ak];
            float lvv[4] = {lv.x, lv.y, lv.z, lv.w};
            float rvv[4] = {rv.x, rv.y, rv.z, rv.w};
#pragma unroll
            for (int r = 0; r < 4; ++r)
#pragma unroll
                for (int c = 0; c < 4; ++c) pacc[r][c] += lvv[r] * rvv[c];
        }
#pragma unroll
        for (int r = 0; r < 4; ++r) {
            float4 bs4 = *(const float4*)&b_s[(size_t)(n0 + an + r) * Nn + k0 + ak];
            float bsv[4] = {bs4.x, bs4.y, bs4.z, bs4.w};
#pragma unroll
            for (int c = 0; c < 4; ++c) {
                float p = pacc[r][c] + bsv[c];
                As[ak + c][an + r] = 1.f / (1.f + __expf(-p));
            }
        }
        __syncthreads();
#pragma unroll
        for (int kk = 0; kk < KB; ++kk) {
            float4 a0 = *(const float4*)&As[kk][ty * 4];
            float4 a1 = *(const float4*)&As[kk][ty * 4 + 64];
            float4 b0 = *(const float4*)&Bs[kk][tx * 4];
            float4 b1 = *(const float4*)&Bs[kk][tx * 4 + 64];
            float av[8] = {a0.x, a0.y, a0.z, a0.w, a1.x, a1.y, a1.z, a1.w};
            float bv[8] = {b0.x, b0.y, b0.z, b0.w, b1.x, b1.y, b1.z, b1.w};
#pragma unroll
            for (int r = 0; r < 8; ++r)
#pragma unroll
                for (int c = 0; c < 8; ++c) acc[r][c] += av[r] * bv[c];
        }
    }
#pragma unroll
    for (int r = 0; r < 8; ++r) {
        int nn = ty * 4 + (r & 3) + ((r >> 2) << 6);
        float4* op = (float4*)(S + ((size_t)(b * Nn + n0 + nn)) * Nn + i0 + tx * 4);
        op[0]  = make_float4(acc[r][0], acc[r][1], acc[r][2], acc[r][3]);
        op[16] = make_float4(acc[r][4], acc[r][5], acc[r][6], acc[r][7]);
    }
}

__global__ __launch_bounds__(256) void k3_colmax(const float* __restrict__ S,
                                                 unsigned* __restrict__ Mkey) {
    int b = blockIdx.z;
    int i0 = blockIdx.x * 64;
    int nbase = blockIdx.y * 256;
    int ii = threadIdx.x & 63, g = threadIdx.x >> 6;
    const float* p = S + ((size_t)(b * Nn + nbase + g * 64)) * Nn + i0 + ii;
    float m = -3.402823466e38f;
#pragma unroll 4
    for (int n = 0; n < 64; ++n) m = fmaxf(m, p[(size_t)n * Nn]);
    __shared__ float red[4][64];
    red[g][ii] = m;
    __syncthreads();
    if (g == 0) {
        m = fmaxf(fmaxf(red[0][ii], red[1][ii]), fmaxf(red[2][ii], red[3][ii]));
        atomicMax(Mkey + b * Nn + i0 + ii, fkey(m));
    }
}

__global__ __launch_bounds__(256) void k4_denom(const float* __restrict__ S,
                                                const unsigned* __restrict__ Mkey,
                                                float* __restrict__ D0) {
    int i0 = blockIdx.x * 64;
    int ii = threadIdx.x & 63, g = threadIdx.x >> 6;
    float M = keyToFloat(Mkey[i0 + ii]);
    const float* p = S + ((size_t)(g * 256)) * Nn + i0 + ii;
    float s = 0.f;
    for (int n = 0; n < 256; ++n) s += __expf(p[(size_t)n * Nn] - M);
    __shared__ float red[4][64];
    red[g][ii] = s;
    __syncthreads();
    if (g == 0) D0[i0 + ii] = (red[0][ii] + red[1][ii]) + (red[2][ii] + red[3][ii]);
}

__global__ __launch_bounds__(256) void k5_final(float* __restrict__ S,
                                                const unsigned* __restrict__ Mkey,
                                                const float* __restrict__ D0) {
    const size_t total4 = (size_t)Bb * Nn * Nn / 4;
    for (size_t idx = (size_t)blockIdx.x * 256 + threadIdx.x; idx < total4;
         idx += (size_t)gridDim.x * 256) {
        size_t e = idx << 2;
        int i = (int)(e & (Nn - 1));
        int b = (int)(e >> 20);
        float4 s4 = ((const float4*)S)[idx];
        uint4 k4 = *(const uint4*)(Mkey + b * Nn + i);
        float4 d4 = *(const float4*)(D0 + i);
        float4 o;
        o.x = __expf(s4.x - keyToFloat(k4.x)) / d4.x;
        o.y = __expf(s4.y - keyToFloat(k4.y)) / d4.y;
        o.z = __expf(s4.z - keyToFloat(k4.z)) / d4.z;
        o.w = __expf(s4.w - keyToFloat(k4.w)) / d4.w;
        ((float4*)S)[idx] = o;
    }
}

extern "C" void kernel_launch(void* const* d_in, const int* in_sizes, int n_in,
                              void* d_out, int out_size, void* d_ws, size_t ws_size,
                              hipStream_t stream) {
    const float* x   = (const float*)d_in[0];
    const float* W1  = (const float*)d_in[1];
    const float* W2  = (const float*)d_in[2];
    const float* W3  = (const float*)d_in[3];
    const float* b_s = (const float*)d_in[4];
    const float* V_s = (const float*)d_in[5];
    float* out = (float*)d_out;
    char* ws = (char*)d_ws;

    if (ws_size >= WS_NEED2) {
        unsigned short* LHSb = (unsigned short*)(ws + LHSB_OFF);
        unsigned short* RHSb = (unsigned short*)(ws + RHSB_OFF);
        unsigned* Mkey = (unsigned*)(ws + MKEY_OFF);
        float* C0 = (float*)(ws + C0_OFF);
        unsigned short* Abf = (unsigned short*)(ws + ABF_OFF);
        unsigned short* Vb  = (unsigned short*)(ws + VB_OFF);
        unsigned short* Eb  = (unsigned short*)(ws + E_OFF);

        k1b<<<Bb * Nn / 4, 256, 0, stream>>>(x, W1, W2, W3, V_s, LHSb, RHSb,
                                             (unsigned*)Vb, Mkey, C0);
        k_sig<<<dim3(4, 4, Bb), 512, 0, stream>>>(LHSb, RHSb, b_s, Abf);
        k2b_8ph<<<512, 512, 0, stream>>>(Abf, Vb, Eb, Mkey, C0);
        k5b<<<2048, 256, 0, stream>>>(Eb, Mkey, C0, out);
    } else {
        float* LHS = (float*)(ws + FB_LHS_OFF);
        float* RHS = (float*)(ws + FB_RHS_OFF);
        unsigned* Mkey = (unsigned*)(ws + FB_MKEY_OFF);
        float* D0 = (float*)(ws + FB_D0_OFF);
        k1_lhs_rhs<<<Bb * Nn / 4, 256, 0, stream>>>(x, W1, W2, W3, LHS, RHS);
        hipMemsetAsync(Mkey, 0, (size_t)Bb * Nn * sizeof(unsigned), stream);
        k2_gemm<<<dim3(Nn / 128, Nn / 128, Bb), 256, 0, stream>>>(LHS, RHS, V_s, b_s, out);
        k3_colmax<<<dim3(Nn / 64, 4, Bb), 256, 0, stream>>>(out, Mkey);
        k4_denom<<<Nn / 64, 256, 0, stream>>>(out, Mkey, D0);
        k5_final<<<2048, 256, 0, stream>>>(out, Mkey, D0);
    }
}